// Round 15
// baseline (778.999 us; speedup 1.0000x reference)
//
#include <hip/hip_runtime.h>
#include <hip/hip_bf16.h>

#define BATCH 1024
#define NLAYER 19
#define DTOT 267696

typedef __attribute__((ext_vector_type(8))) short v8s;
typedef __attribute__((ext_vector_type(4))) float v4f;

__device__ inline float ldf(const float* p){ return *p; }
__device__ inline float ldf(const __hip_bfloat16* p){ return __bfloat162float(*p); }

__device__ inline unsigned short f2bf(float x){
    __hip_bfloat16 h = __float2bfloat16(x);
    return *reinterpret_cast<unsigned short*>(&h);
}
__device__ inline float bf2f(unsigned int u){
    return __uint_as_float(u << 16);
}

// ---- dtype detector: flag=1 if inputs bf16, 0 if f32 ----
__global__ void detect_kernel(const unsigned short* __restrict__ xraw, int* __restrict__ flag)
{
    __shared__ int bad;
    if (threadIdx.x == 0) bad = 0;
    __syncthreads();
    int lbad = 0;
    for (int i = threadIdx.x; i < 4096; i += 256) {
        unsigned e = (xraw[i] >> 7) & 0xFF;
        if (e >= 147) lbad++;
    }
    if (lbad) atomicAdd(&bad, lbad);
    __syncthreads();
    if (threadIdx.x == 0) *flag = (bad == 0) ? 1 : 0;
}

__device__ inline bool flag_skip(const int* flag, int want)
{
    if (flag == nullptr) return false;
    return (*(volatile const int*)flag) != want;
}

// w_flat = origin + new_param @ P
template<typename T>
__global__ void wflat_kernel(const T* __restrict__ origin,
                             const T* __restrict__ P,
                             const T* __restrict__ npar,
                             float* __restrict__ wout, int D,
                             const int* flag, int want)
{
    if (flag_skip(flag, want)) return;
    int d = blockIdx.x*256 + threadIdx.x;
    if (d >= D) return;
    float acc = ldf(origin + d);
    #pragma unroll 8
    for (int k = 0; k < 40; k++)
        acc += ldf(npar + k) * ldf(P + (long long)k*D + d);
    wout[d] = acc;
}

// ---- weight transform: wflat (OIHW fp32) -> W_T[l][cout][kpad] bf16, k = tap*Cin+ci
__global__ void wprep_kernel(const float* __restrict__ wflat, unsigned short* __restrict__ WT)
{
    static const int CINA[19]  = {3,16,16,16,16,16,16,16,32,32,32,32,32,32,64,64,64,64,64};
    static const int COUTA[19] = {16,16,16,16,16,16,16,32,32,32,32,32,32,64,64,64,64,64,64};
    static const int LGCA[19]  = {0,4,4,4,4,4,4,4,5,5,5,5,5,5,6,6,6,6,6};
    static const int KPADA[19] = {0,160,160,160,160,160,160,160,288,288,288,288,288,288,576,576,576,576,576};
    static const int WOFFA[19] = {0,432,2736,5040,7344,9648,11952,14256,18864,
        28080,37296,46512,55728,64944,83376,120240,157104,193968,230832};
    static const int WTOFFA[19]= {0,0,2560,5120,7680,10240,12800,15360,20480,29696,
        38912,48128,57344,66560,84992,121856,158720,195584,232448};
    int l = blockIdx.z;
    if (l == 0) return;
    int co = blockIdx.y;
    if (co >= COUTA[l]) return;
    int kp = blockIdx.x*192 + threadIdx.x;
    if (kp >= KPADA[l]) return;
    int cin = CINA[l];
    float v = 0.f;
    if (kp < 9*cin) {
        int tap = kp >> LGCA[l];
        int ci  = kp & (cin - 1);
        v = wflat[WOFFA[l] + (co*cin + ci)*9 + tap];
    }
    WT[WTOFFA[l] + co*KPADA[l] + kp] = f2bf(v);
}

__device__ inline void ldpair(const float* base, int p, float& x0, float& x1){
    const float2 v = ((const float2*)base)[p];
    x0 = v.x; x1 = v.y;
}
__device__ inline void ldpair(const __hip_bfloat16* base, int p, float& x0, float& x1){
    unsigned u = ((const unsigned int*)base)[p];
    x0 = __uint_as_float(u << 16);
    x1 = __uint_as_float(u & 0xffff0000u);
}

// ---- layer 0: direct conv (Cin=3), NCHW input -> NHWC bf16 raw ----
template<typename T>
__global__ __launch_bounds__(512) void conv_l0(
    const T* __restrict__ in, const float* __restrict__ wt,
    unsigned short* __restrict__ out,
    const int* flag, int want)
{
    if (flag_skip(flag, want)) return;
    constexpr int WP = 38, W2 = 19;
    __shared__ uint2 smem2[2048];
    __shared__ unsigned int in_su[3*18*W2];
    __shared__ float w_s[432];

    const int tid  = threadIdx.x;
    const int b    = blockIdx.x >> 1;
    const int half = blockIdx.x & 1;
    const int row0 = half*16 - 1;

    {
        const T* inb = in + (size_t)b*3072;
        for (int i = tid; i < 864; i += 512) {
            int w2 = i & 15, lr = (i >> 4) % 18, c = i / 288;
            int ih = row0 + lr;
            unsigned int pk = 0u;
            if ((unsigned)ih < 32u) {
                float x0, x1;
                ldpair(inb, (c*32 + ih)*16 + w2, x0, x1);
                pk = (unsigned int)f2bf(x0) | ((unsigned int)f2bf(x1) << 16);
            }
            in_su[(c*18 + lr)*W2 + 1 + w2] = pk;
        }
        unsigned short* in_ss = (unsigned short*)in_su;
        for (int i = tid; i < 54; i += 512) {
            in_ss[i*WP + 1]  = 0;
            in_ss[i*WP + 34] = 0;
        }
        for (int i = tid; i < 432; i += 512) w_s[i] = wt[i];
    }
    __syncthreads();

    const int r   = tid >> 5;
    const int col = tid & 31;

    float acc[16];
    #pragma unroll
    for (int c = 0; c < 16; c++) acc[c] = 0.f;

    #pragma unroll
    for (int ci = 0; ci < 3; ci++) {
        #pragma unroll
        for (int kh = 0; kh < 3; kh++) {
            const unsigned int* up = in_su + (ci*18 + r + kh)*W2 + ((col+1) >> 1);
            unsigned int u0 = up[0], u1 = up[1];
            bool odd = (col & 1);
            float s1 = odd ? bf2f(u0 & 0xffffu) : bf2f(u0 >> 16);
            float s2 = odd ? bf2f(u0 >> 16)     : bf2f(u1 & 0xffffu);
            float s3 = odd ? bf2f(u1 & 0xffffu) : bf2f(u1 >> 16);
            const float* wp = w_s + ci*9 + kh*3;
            #pragma unroll
            for (int co = 0; co < 16; co++) {
                acc[co] += s1*wp[co*27+0] + s2*wp[co*27+1] + s3*wp[co*27+2];
            }
        }
    }

    #pragma unroll
    for (int j = 0; j < 4; j++) {
        uint2 v;
        v.x = (unsigned)f2bf(acc[4*j+0]) | ((unsigned)f2bf(acc[4*j+1]) << 16);
        v.y = (unsigned)f2bf(acc[4*j+2]) | ((unsigned)f2bf(acc[4*j+3]) << 16);
        smem2[tid*4 + (j ^ (tid & 3))] = v;
    }
    __syncthreads();
    {
        uint2* ob = (uint2*)(out + (size_t)b*16384 + half*8192);
        #pragma unroll
        for (int it = 0; it < 4; it++) {
            int s = it*512 + tid;
            int phys = (s & ~3) | ((s & 3) ^ ((s >> 2) & 3));
            ob[s] = smem2[phys];
        }
    }
}

// ---- per-channel sum/sumsq over NHWC bf16, C=16; 32 atomics/block ----
__global__ __launch_bounds__(256) void stats16_kernel(
    const unsigned short* __restrict__ x, float* __restrict__ stats, int n4)
{
    __shared__ float red[4][32];
    int t = blockIdx.x*256 + threadIdx.x;
    const int stride = gridDim.x*256;
    float s[4] = {0,0,0,0}, q[4] = {0,0,0,0};
    for (int i = t; i < n4; i += stride) {
        uint2 v = ((const uint2*)x)[i];
        float f0 = bf2f(v.x & 0xffffu), f1 = bf2f(v.x >> 16);
        float f2_ = bf2f(v.y & 0xffffu), f3 = bf2f(v.y >> 16);
        s[0] += f0; q[0] += f0*f0;
        s[1] += f1; q[1] += f1*f1;
        s[2] += f2_; q[2] += f2_*f2_;
        s[3] += f3; q[3] += f3*f3;
    }
    #pragma unroll
    for (int off = 4; off < 64; off <<= 1) {
        #pragma unroll
        for (int k = 0; k < 4; k++) {
            s[k] += __shfl_xor(s[k], off);
            q[k] += __shfl_xor(q[k], off);
        }
    }
    const int lane = threadIdx.x & 63, w = threadIdx.x >> 6;
    if (lane < 4) {
        #pragma unroll
        for (int k = 0; k < 4; k++) {
            red[w][lane*4 + k]      = s[k];
            red[w][16 + lane*4 + k] = q[k];
        }
    }
    __syncthreads();
    if (threadIdx.x < 32) {
        float v = red[0][threadIdx.x] + red[1][threadIdx.x]
                + red[2][threadIdx.x] + red[3][threadIdx.x];
        atomicAdd(&stats[(threadIdx.x < 16) ? threadIdx.x : (48 + threadIdx.x)], v);
    }
}

// ---- MFMA implicit-GEMM 3x3 conv, one block (4 waves) per image ----
// Barrier-free K-loop: all tiles accumulated in registers (<=16 v4f), then
// ONE barrier -> write full output into in_s (reused) -> barrier -> one
// contiguous cooperative store. 3 barriers total (was 2 per tile pair).
template<int CIN, int COUT, int HIN, int WIN, int ST>
__global__ __launch_bounds__(256, (COUT==16)?3:4) void conv_mfma(
    const unsigned short* __restrict__ src, const unsigned short* __restrict__ wt,
    unsigned short* __restrict__ out, float* __restrict__ stats,
    const float* __restrict__ nstats, float ninvN)
{
    constexpr int HO = HIN/ST, WO = WIN/ST, M = HO*WO, MT = M/16;
    constexpr int NT = COUT/16;
    constexpr int K  = 9*CIN;
    constexpr int S  = (K + 31)/32;
    constexpr int KPAD = S*32;
    constexpr int lgC  = (CIN==16)?4:(CIN==32)?5:6;
    constexpr int lgWI = (WIN==32)?5:(WIN==16)?4:3;
    constexpr int lgWO = (WO==32)?5:(WO==16)?4:3;
    constexpr int CMASK = CIN/8 - 1;
    constexpr int JITER = (NT==1)? MT/4 : (NT==2)? MT/2 : MT;
    static_assert(M*COUT <= CIN*HIN*WIN, "out_s fits in in_s");

    __shared__ unsigned short in_s[CIN*HIN*WIN];   // input, then output bounce
    __shared__ float red[128];
    __shared__ float nm[64], nv[64];
    __shared__ uint4 zq;

    const int tid = threadIdx.x;
    const int b   = blockIdx.x;

    if (tid == 0) { zq.x = 0; zq.y = 0; zq.z = 0; zq.w = 0; }
    if (nstats != nullptr && tid < CIN) {
        float m = nstats[tid]*ninvN;
        float v = fmaxf(nstats[64+tid]*ninvN - m*m, 0.f);
        nm[tid] = m; nv[tid] = rsqrtf(v + 1e-5f);
    }
    __syncthreads();

    // stage NHWC bf16 -> swizzled LDS, uint4 per iteration
    {
        const uint4* sb4 = (const uint4*)(src + (size_t)b*(HIN*WIN)*CIN);
        constexpr int NP4 = CIN*HIN*WIN/8;
        if (nstats == nullptr) {
            for (int i = tid; i < NP4; i += 256) {
                uint4 v = sb4[i];
                int e0 = i << 3;
                int c0 = e0 & (CIN-1);
                int p  = e0 >> lgC;
                int csw = c0 ^ ((p & CMASK) << 3);
                *(uint4*)(in_s + (p << lgC) + csw) = v;
            }
        } else {
            for (int i = tid; i < NP4; i += 256) {
                uint4 v = sb4[i];
                int e0 = i << 3;
                int c0 = e0 & (CIN-1);
                int p  = e0 >> lgC;
                float f[8] = { bf2f(v.x & 0xffffu), bf2f(v.x >> 16),
                               bf2f(v.y & 0xffffu), bf2f(v.y >> 16),
                               bf2f(v.z & 0xffffu), bf2f(v.z >> 16),
                               bf2f(v.w & 0xffffu), bf2f(v.w >> 16) };
                #pragma unroll
                for (int k = 0; k < 8; k++) {
                    int c = c0 + k;
                    f[k] = fmaxf((f[k] - nm[c])*nv[c], 0.f);
                }
                uint4 o;
                o.x = (unsigned)f2bf(f[0]) | ((unsigned)f2bf(f[1]) << 16);
                o.y = (unsigned)f2bf(f[2]) | ((unsigned)f2bf(f[3]) << 16);
                o.z = (unsigned)f2bf(f[4]) | ((unsigned)f2bf(f[5]) << 16);
                o.w = (unsigned)f2bf(f[6]) | ((unsigned)f2bf(f[7]) << 16);
                int csw = c0 ^ ((p & CMASK) << 3);
                *(uint4*)(in_s + (p << lgC) + csw) = o;
            }
        }
    }
    __syncthreads();

    const int w   = tid >> 6;
    const int ln  = tid & 63;
    const int l15 = ln & 15;
    const int q   = ln >> 4;

    int n0, mt0, step;
    if (NT == 1)      { n0 = 0;         mt0 = w;      step = 4; }
    else if (NT == 2) { n0 = (w&1)*16;  mt0 = w>>1;   step = 2; }
    else              { n0 = w*16;      mt0 = 0;      step = 1; }

    v8s Bf[S];
    {
        const unsigned short* wb = wt + (size_t)(n0 + l15)*KPAD + q*8;
        #pragma unroll
        for (int s = 0; s < S; s++)
            Bf[s] = *(const v8s*)(wb + 32*s);
    }

    int dh1s[S], dw1s[S];
    int c0q = (CIN==16) ? ((q & 1) << 3) : (q << 3);
    if (CIN == 16) {
        int tq = q >> 1;
        #pragma unroll
        for (int s = 0; s < S; s++) {
            int tap = 2*s + tq;
            int dh = (tap*11) >> 5;
            int dw = tap - 3*dh;
            dh1s[s] = (tap >= 9) ? -1000 : (dh - 1);
            dw1s[s] = dw - 1;
        }
    }

    // barrier-free K-loop: all tiles in registers
    v4f acc[JITER];
    #pragma unroll
    for (int j = 0; j < JITER; j++) acc[j] = v4f{0.f,0.f,0.f,0.f};

    #pragma unroll
    for (int j = 0; j < JITER; j++) {
        const int mt  = mt0 + j*step;
        const int p   = mt*16 + l15;
        const int ihb = (p >> lgWO) * ST;
        const int iwb = (p & (WO-1)) * ST;
        #pragma unroll
        for (int s = 0; s < S; s++) {
            int dh1, dw1, c0s;
            if (CIN == 16) { dh1 = dh1s[s]; dw1 = dw1s[s]; c0s = c0q; }
            else {
                const int tap = (CIN == 32) ? s : (s >> 1);
                dh1 = tap/3 - 1; dw1 = tap%3 - 1;
                c0s = c0q + ((CIN == 64) ? ((s & 1) << 5) : 0);
            }
            int ih = ihb + dh1, iw = iwb + dw1;
            bool valid = ((unsigned)ih < (unsigned)HIN) && ((unsigned)iw < (unsigned)WIN);
            int pp  = (ih << lgWI) + iw;
            int csw = c0s ^ ((pp & CMASK) << 3);
            int eoff = (pp << lgC) + csw;
            const v8s* ap = valid ? (const v8s*)(in_s + eoff) : (const v8s*)&zq;
            v8s Af = *ap;
            acc[j] = __builtin_amdgcn_mfma_f32_16x16x32_bf16(Af, Bf[s], acc[j], 0, 0, 0);
        }
    }
    __syncthreads();   // all in_s reads complete -> reuse as output bounce

    unsigned short* out_s = in_s;
    float sa = 0.f, qa = 0.f;
    #pragma unroll
    for (int j = 0; j < JITER; j++) {
        const int mt = mt0 + j*step;
        #pragma unroll
        for (int r2 = 0; r2 < 4; r2++) {
            float v = acc[j][r2];
            out_s[(mt*16 + q*4 + r2)*COUT + n0 + l15] = f2bf(v);
            sa += v; qa += v*v;
        }
    }
    __syncthreads();

    // one contiguous cooperative store of the full image output
    {
        constexpr int NIT = (M*COUT/8)/256;
        uint4* ob4 = (uint4*)(out + (size_t)b*M*COUT);
        const uint4* os4 = (const uint4*)in_s;
        #pragma unroll
        for (int it = 0; it < NIT; it++)
            ob4[it*256 + tid] = os4[it*256 + tid];
    }

    // stats: quad reduce -> per-wave deposit -> combine -> 2 atomics/channel
    sa += __shfl_xor(sa, 16); sa += __shfl_xor(sa, 32);
    qa += __shfl_xor(qa, 16); qa += __shfl_xor(qa, 32);
    if (q == 0) {
        red[(w*16 + l15)*2]     = sa;
        red[(w*16 + l15)*2 + 1] = qa;
    }
    __syncthreads();
    if (tid < COUT) {
        float S2, Q2;
        if (NT == 1) {
            S2 = red[tid*2] + red[(16+tid)*2] + red[(32+tid)*2] + red[(48+tid)*2];
            Q2 = red[tid*2+1] + red[(16+tid)*2+1] + red[(32+tid)*2+1] + red[(48+tid)*2+1];
        } else if (NT == 2) {
            int w0 = tid >> 4, cl = tid & 15;
            S2 = red[((w0*16)+cl)*2]     + red[(((w0+2)*16)+cl)*2];
            Q2 = red[((w0*16)+cl)*2 + 1] + red[(((w0+2)*16)+cl)*2 + 1];
        } else {
            int w0 = tid >> 4, cl = tid & 15;
            S2 = red[((w0*16)+cl)*2];
            Q2 = red[((w0*16)+cl)*2 + 1];
        }
        atomicAdd(&stats[tid],      S2);
        atomicAdd(&stats[64 + tid], Q2);
    }
}

// y = relu(bn(x) + shortcut(prev)); all NHWC bf16; 4 elements/thread
template<int lgC, int lgHW, int lgW, int ST, bool PN>
__global__ __launch_bounds__(256) void bn_add_relu_nhwc(
    const unsigned short* __restrict__ x,
    const unsigned short* __restrict__ prev,
    unsigned short* __restrict__ outp,
    const float* __restrict__ stats, const float* __restrict__ pstats,
    int prevC, int padF, float invN, float pinvN, int n4)
{
    int i4 = blockIdx.x*256 + threadIdx.x;
    if (i4 >= n4) return;
    constexpr int C = 1<<lgC, HW = 1<<lgHW, W = 1<<lgW;
    const int i  = i4*4;
    const int c0 = i & (C-1);
    const int p  = (i >> lgC) & (HW-1);
    const int b  = i >> (lgC + lgHW);

    uint2 xv = ((const uint2*)x)[i4];
    float xf[4] = { bf2f(xv.x & 0xffffu), bf2f(xv.x >> 16),
                    bf2f(xv.y & 0xffffu), bf2f(xv.y >> 16) };
    float sc[4];
    if (ST == 1) {
        uint2 pv = ((const uint2*)prev)[i4];
        sc[0] = bf2f(pv.x & 0xffffu); sc[1] = bf2f(pv.x >> 16);
        sc[2] = bf2f(pv.y & 0xffffu); sc[3] = bf2f(pv.y >> 16);
        if (PN) {
            #pragma unroll
            for (int k = 0; k < 4; k++) {
                int c = c0 + k;
                float pm = pstats[c]*pinvN;
                float pvv = fmaxf(pstats[64+c]*pinvN - pm*pm, 0.f);
                sc[k] = fmaxf((sc[k] - pm)*rsqrtf(pvv + 1e-5f), 0.f);
            }
        }
    } else {
        int h = p >> lgW, wq = p & (W-1);
        int pp = (h << (lgW+2)) + 2*wq;
        #pragma unroll
        for (int k = 0; k < 4; k++) {
            int pc = c0 + k - padF;
            sc[k] = (pc >= 0 && pc < prevC)
                  ? bf2f((unsigned int)prev[((size_t)b*(HW*4) + pp)*prevC + pc]) : 0.f;
        }
    }
    float o[4];
    #pragma unroll
    for (int k = 0; k < 4; k++) {
        int c = c0 + k;
        float m = stats[c]*invN;
        float v = fmaxf(stats[64+c]*invN - m*m, 0.f);
        o[k] = fmaxf((xf[k]-m)*rsqrtf(v + 1e-5f) + sc[k], 0.f);
    }
    uint2 ov;
    ov.x = (unsigned)f2bf(o[0]) | ((unsigned)f2bf(o[1]) << 16);
    ov.y = (unsigned)f2bf(o[2]) | ((unsigned)f2bf(o[3]) << 16);
    ((uint2*)outp)[i4] = ov;
}

__device__ inline void stf(float* p, float v){ *p = v; }
__device__ inline void stf(__hip_bfloat16* p, float v){ *p = __float2bfloat16(v); }

// mean over 8x8 spatial (NHWC bf16) -> (B,64); out = feat @ Wfc^T + bfc -> (B,10)
template<typename T>
__global__ void poolfc_kernel(const unsigned short* __restrict__ in,
    const T* __restrict__ Wfc, const T* __restrict__ bfc,
    T* __restrict__ out, const int* flag, int want)
{
    if (flag_skip(flag, want)) return;
    int b = blockIdx.x;
    int c = threadIdx.x; // 64 threads
    float s = 0.f;
    #pragma unroll
    for (int p = 0; p < 64; p++) s += bf2f((unsigned int)in[((size_t)b*64 + p)*64 + c]);
    __shared__ float feat[64];
    feat[c] = s * (1.f/64.f);
    __syncthreads();
    if (c < 10) {
        float o = ldf(bfc + c);
        for (int k = 0; k < 64; k++)
            o += feat[k] * ldf(Wfc + c*64 + k);
        stf(out + b*10 + c, o);
    }
}

extern "C" void kernel_launch(void* const* d_in, const int* in_sizes, int n_in,
                              void* d_out, int out_size, void* d_ws, size_t ws_size,
                              hipStream_t stream)
{
    char* ws = (char*)d_ws;
    float* wflat = (float*)(ws);                            // DTOT fp32
    float* stats = (float*)(ws + 1114112);                  // 19 x 256 fp32
    int*   flag  = (int*)  (ws + 1146880);
    unsigned short* WT = (unsigned short*)(ws + 1179648);   // 269312 bf16
    unsigned short* curA = (unsigned short*)(ws + 1720320);               // 33.5MB bf16 NHWC
    unsigned short* curB = (unsigned short*)(ws + 1720320 + 33554432ULL); // 33.5MB (l0 raw)
    unsigned short* f1   = (unsigned short*)(ws + 1720320 + 67108864ULL);
    unsigned short* f2   = (unsigned short*)(ws + 1720320 + 100663296ULL);

    hipMemsetAsync(stats, 0, 32768, stream);
    detect_kernel<<<1, 256, 0, stream>>>((const unsigned short*)d_in[0], flag);

    wflat_kernel<__hip_bfloat16><<<(DTOT+255)/256, 256, 0, stream>>>(
        (const __hip_bfloat16*)d_in[1], (const __hip_bfloat16*)d_in[2],
        (const __hip_bfloat16*)d_in[3], wflat, DTOT, flag, 1);
    wflat_kernel<float><<<(DTOT+255)/256, 256, 0, stream>>>(
        (const float*)d_in[1], (const float*)d_in[2],
        (const float*)d_in[3], wflat, DTOT, flag, 0);

    {
        dim3 g(3, 64, 19);
        wprep_kernel<<<g, 192, 0, stream>>>(wflat, WT);
    }

    static const int WTOFF[NLAYER] = {0,0,2560,5120,7680,10240,12800,15360,20480,29696,
        38912,48128,57344,66560,84992,121856,158720,195584,232448};
    const float iN32 = 1.f/1048576.f;   // B*32*32
    const float iN16 = 1.f/262144.f;    // B*16*16
    const float iN8  = 1.f/65536.f;     // B*8*8

    // ---- layer 0: direct conv -> NHWC bf16 raw (curB); stats in separate pass
    conv_l0<__hip_bfloat16><<<2*BATCH,512,0,stream>>>(
        (const __hip_bfloat16*)d_in[0], wflat, curB, flag, 1);
    conv_l0<float><<<2*BATCH,512,0,stream>>>(
        (const float*)d_in[0], wflat, curB, flag, 0);
    stats16_kernel<<<512,256,0,stream>>>(curB, stats, 4194304);

    unsigned short* cur   = curB;   // raw l0 (block 0 normalizes on the fly)
    unsigned short* other = curA;

    // block 0 (normalizing consumers), blocks 1-2 standard
    for (int bi = 0; bi < 3; bi++) {
        int la = 1 + bi*2, lb = 2 + bi*2;
        const float* nst = (bi == 0) ? stats : nullptr;
        conv_mfma<16,16,32,32,1><<<BATCH,256,0,stream>>>(
            cur, WT + WTOFF[la], f1, stats + la*256, nst, iN32);
        conv_mfma<16,16,32,32,1><<<BATCH,256,0,stream>>>(
            f1, WT + WTOFF[lb], f2, stats + lb*256, stats + la*256, iN32);
        if (bi == 0)
            bn_add_relu_nhwc<4,10,5,1,true><<<16384,256,0,stream>>>(
                f2, cur, other, stats + lb*256, stats, 16, 0, iN32, iN32, 4194304);
        else
            bn_add_relu_nhwc<4,10,5,1,false><<<16384,256,0,stream>>>(
                f2, cur, other, stats + lb*256, nullptr, 16, 0, iN32, 0.f, 4194304);
        unsigned short* t = other; other = cur; cur = t;
    }
    // block 3: stride2 16->32ch, 32x32 -> 16x16
    conv_mfma<16,32,32,32,2><<<BATCH,256,0,stream>>>(
        cur, WT + WTOFF[7], f1, stats + 7*256, nullptr, 0.f);
    conv_mfma<32,32,16,16,1><<<BATCH,256,0,stream>>>(
        f1, WT + WTOFF[8], f2, stats + 8*256, stats + 7*256, iN16);
    bn_add_relu_nhwc<5,8,4,2,false><<<8192,256,0,stream>>>(
        f2, cur, other, stats + 8*256, nullptr, 16, 8, iN16, 0.f, 2097152);
    { unsigned short* t = other; other = cur; cur = t; }
    // blocks 4-5: 32ch 16x16
    for (int bi = 0; bi < 2; bi++) {
        int la = 9 + bi*2, lb = 10 + bi*2;
        conv_mfma<32,32,16,16,1><<<BATCH,256,0,stream>>>(
            cur, WT + WTOFF[la], f1, stats + la*256, nullptr, 0.f);
        conv_mfma<32,32,16,16,1><<<BATCH,256,0,stream>>>(
            f1, WT + WTOFF[lb], f2, stats + lb*256, stats + la*256, iN16);
        bn_add_relu_nhwc<5,8,4,1,false><<<8192,256,0,stream>>>(
            f2, cur, other, stats + lb*256, nullptr, 32, 0, iN16, 0.f, 2097152);
        unsigned short* t = other; other = cur; cur = t;
    }
    // block 6: stride2 32->64ch, 16x16 -> 8x8
    conv_mfma<32,64,16,16,2><<<BATCH,256,0,stream>>>(
        cur, WT + WTOFF[13], f1, stats + 13*256, nullptr, 0.f);
    conv_mfma<64,64,8,8,1><<<BATCH,256,0,stream>>>(
        f1, WT + WTOFF[14], f2, stats + 14*256, stats + 13*256, iN8);
    bn_add_relu_nhwc<6,6,3,2,false><<<4096,256,0,stream>>>(
        f2, cur, other, stats + 14*256, nullptr, 32, 16, iN8, 0.f, 1048576);
    { unsigned short* t = other; other = cur; cur = t; }
    // blocks 7-8: 64ch 8x8
    for (int bi = 0; bi < 2; bi++) {
        int la = 15 + bi*2, lb = 16 + bi*2;
        conv_mfma<64,64,8,8,1><<<BATCH,256,0,stream>>>(
            cur, WT + WTOFF[la], f1, stats + la*256, nullptr, 0.f);
        conv_mfma<64,64,8,8,1><<<BATCH,256,0,stream>>>(
            f1, WT + WTOFF[lb], f2, stats + lb*256, stats + la*256, iN8);
        bn_add_relu_nhwc<6,6,3,1,false><<<4096,256,0,stream>>>(
            f2, cur, other, stats + lb*256, nullptr, 64, 0, iN8, 0.f, 1048576);
        unsigned short* t = other; other = cur; cur = t;
    }

    poolfc_kernel<__hip_bfloat16><<<BATCH, 64, 0, stream>>>(
        cur, (const __hip_bfloat16*)d_in[4], (const __hip_bfloat16*)d_in[5],
        (__hip_bfloat16*)d_out, flag, 1);
    poolfc_kernel<float><<<BATCH, 64, 0, stream>>>(
        cur, (const float*)d_in[4], (const float*)d_in[5],
        (float*)d_out, flag, 0);
}

// Round 16
// 728.170 us; speedup vs baseline: 1.0698x; 1.0698x over previous
//
#include <hip/hip_runtime.h>
#include <hip/hip_bf16.h>

#define BATCH 1024
#define NLAYER 19
#define DTOT 267696

typedef __attribute__((ext_vector_type(8))) short v8s;
typedef __attribute__((ext_vector_type(4))) float v4f;

__device__ inline float ldf(const float* p){ return *p; }
__device__ inline float ldf(const __hip_bfloat16* p){ return __bfloat162float(*p); }

__device__ inline unsigned short f2bf(float x){
    __hip_bfloat16 h = __float2bfloat16(x);
    return *reinterpret_cast<unsigned short*>(&h);
}
__device__ inline float bf2f(unsigned int u){
    return __uint_as_float(u << 16);
}

// ---- dtype detector: flag=1 if inputs bf16, 0 if f32 ----
__global__ void detect_kernel(const unsigned short* __restrict__ xraw, int* __restrict__ flag)
{
    __shared__ int bad;
    if (threadIdx.x == 0) bad = 0;
    __syncthreads();
    int lbad = 0;
    for (int i = threadIdx.x; i < 4096; i += 256) {
        unsigned e = (xraw[i] >> 7) & 0xFF;
        if (e >= 147) lbad++;
    }
    if (lbad) atomicAdd(&bad, lbad);
    __syncthreads();
    if (threadIdx.x == 0) *flag = (bad == 0) ? 1 : 0;
}

__device__ inline bool flag_skip(const int* flag, int want)
{
    if (flag == nullptr) return false;
    return (*(volatile const int*)flag) != want;
}

// w_flat = origin + new_param @ P
template<typename T>
__global__ void wflat_kernel(const T* __restrict__ origin,
                             const T* __restrict__ P,
                             const T* __restrict__ npar,
                             float* __restrict__ wout, int D,
                             const int* flag, int want)
{
    if (flag_skip(flag, want)) return;
    int d = blockIdx.x*256 + threadIdx.x;
    if (d >= D) return;
    float acc = ldf(origin + d);
    #pragma unroll 8
    for (int k = 0; k < 40; k++)
        acc += ldf(npar + k) * ldf(P + (long long)k*D + d);
    wout[d] = acc;
}

// ---- weight transform: wflat (OIHW fp32) -> W_T[l][cout][kpad] bf16, k = tap*Cin+ci
__global__ void wprep_kernel(const float* __restrict__ wflat, unsigned short* __restrict__ WT)
{
    static const int CINA[19]  = {3,16,16,16,16,16,16,16,32,32,32,32,32,32,64,64,64,64,64};
    static const int COUTA[19] = {16,16,16,16,16,16,16,32,32,32,32,32,32,64,64,64,64,64,64};
    static const int LGCA[19]  = {0,4,4,4,4,4,4,4,5,5,5,5,5,5,6,6,6,6,6};
    static const int KPADA[19] = {0,160,160,160,160,160,160,160,288,288,288,288,288,288,576,576,576,576,576};
    static const int WOFFA[19] = {0,432,2736,5040,7344,9648,11952,14256,18864,
        28080,37296,46512,55728,64944,83376,120240,157104,193968,230832};
    static const int WTOFFA[19]= {0,0,2560,5120,7680,10240,12800,15360,20480,29696,
        38912,48128,57344,66560,84992,121856,158720,195584,232448};
    int l = blockIdx.z;
    if (l == 0) return;
    int co = blockIdx.y;
    if (co >= COUTA[l]) return;
    int kp = blockIdx.x*192 + threadIdx.x;
    if (kp >= KPADA[l]) return;
    int cin = CINA[l];
    float v = 0.f;
    if (kp < 9*cin) {
        int tap = kp >> LGCA[l];
        int ci  = kp & (cin - 1);
        v = wflat[WOFFA[l] + (co*cin + ci)*9 + tap];
    }
    WT[WTOFFA[l] + co*KPADA[l] + kp] = f2bf(v);
}

__device__ inline void ldpair(const float* base, int p, float& x0, float& x1){
    const float2 v = ((const float2*)base)[p];
    x0 = v.x; x1 = v.y;
}
__device__ inline void ldpair(const __hip_bfloat16* base, int p, float& x0, float& x1){
    unsigned u = ((const unsigned int*)base)[p];
    x0 = __uint_as_float(u << 16);
    x1 = __uint_as_float(u & 0xffff0000u);
}

// ---- layer 0: direct conv (Cin=3), NCHW input -> NHWC bf16 raw ----
template<typename T>
__global__ __launch_bounds__(512) void conv_l0(
    const T* __restrict__ in, const float* __restrict__ wt,
    unsigned short* __restrict__ out,
    const int* flag, int want)
{
    if (flag_skip(flag, want)) return;
    constexpr int WP = 38, W2 = 19;
    __shared__ uint2 smem2[2048];
    __shared__ unsigned int in_su[3*18*W2];
    __shared__ float w_s[432];

    const int tid  = threadIdx.x;
    const int b    = blockIdx.x >> 1;
    const int half = blockIdx.x & 1;
    const int row0 = half*16 - 1;

    {
        const T* inb = in + (size_t)b*3072;
        for (int i = tid; i < 864; i += 512) {
            int w2 = i & 15, lr = (i >> 4) % 18, c = i / 288;
            int ih = row0 + lr;
            unsigned int pk = 0u;
            if ((unsigned)ih < 32u) {
                float x0, x1;
                ldpair(inb, (c*32 + ih)*16 + w2, x0, x1);
                pk = (unsigned int)f2bf(x0) | ((unsigned int)f2bf(x1) << 16);
            }
            in_su[(c*18 + lr)*W2 + 1 + w2] = pk;
        }
        unsigned short* in_ss = (unsigned short*)in_su;
        for (int i = tid; i < 54; i += 512) {
            in_ss[i*WP + 1]  = 0;
            in_ss[i*WP + 34] = 0;
        }
        for (int i = tid; i < 432; i += 512) w_s[i] = wt[i];
    }
    __syncthreads();

    const int r   = tid >> 5;
    const int col = tid & 31;

    float acc[16];
    #pragma unroll
    for (int c = 0; c < 16; c++) acc[c] = 0.f;

    #pragma unroll
    for (int ci = 0; ci < 3; ci++) {
        #pragma unroll
        for (int kh = 0; kh < 3; kh++) {
            const unsigned int* up = in_su + (ci*18 + r + kh)*W2 + ((col+1) >> 1);
            unsigned int u0 = up[0], u1 = up[1];
            bool odd = (col & 1);
            float s1 = odd ? bf2f(u0 & 0xffffu) : bf2f(u0 >> 16);
            float s2 = odd ? bf2f(u0 >> 16)     : bf2f(u1 & 0xffffu);
            float s3 = odd ? bf2f(u1 & 0xffffu) : bf2f(u1 >> 16);
            const float* wp = w_s + ci*9 + kh*3;
            #pragma unroll
            for (int co = 0; co < 16; co++) {
                acc[co] += s1*wp[co*27+0] + s2*wp[co*27+1] + s3*wp[co*27+2];
            }
        }
    }

    #pragma unroll
    for (int j = 0; j < 4; j++) {
        uint2 v;
        v.x = (unsigned)f2bf(acc[4*j+0]) | ((unsigned)f2bf(acc[4*j+1]) << 16);
        v.y = (unsigned)f2bf(acc[4*j+2]) | ((unsigned)f2bf(acc[4*j+3]) << 16);
        smem2[tid*4 + (j ^ (tid & 3))] = v;
    }
    __syncthreads();
    {
        uint2* ob = (uint2*)(out + (size_t)b*16384 + half*8192);
        #pragma unroll
        for (int it = 0; it < 4; it++) {
            int s = it*512 + tid;
            int phys = (s & ~3) | ((s & 3) ^ ((s >> 2) & 3));
            ob[s] = smem2[phys];
        }
    }
}

// ---- per-channel sum/sumsq over NHWC bf16, C=16; 32 atomics/block ----
__global__ __launch_bounds__(256) void stats16_kernel(
    const unsigned short* __restrict__ x, float* __restrict__ stats, int n4)
{
    __shared__ float red[4][32];
    int t = blockIdx.x*256 + threadIdx.x;
    const int stride = gridDim.x*256;
    float s[4] = {0,0,0,0}, q[4] = {0,0,0,0};
    for (int i = t; i < n4; i += stride) {
        uint2 v = ((const uint2*)x)[i];
        float f0 = bf2f(v.x & 0xffffu), f1 = bf2f(v.x >> 16);
        float f2_ = bf2f(v.y & 0xffffu), f3 = bf2f(v.y >> 16);
        s[0] += f0; q[0] += f0*f0;
        s[1] += f1; q[1] += f1*f1;
        s[2] += f2_; q[2] += f2_*f2_;
        s[3] += f3; q[3] += f3*f3;
    }
    #pragma unroll
    for (int off = 4; off < 64; off <<= 1) {
        #pragma unroll
        for (int k = 0; k < 4; k++) {
            s[k] += __shfl_xor(s[k], off);
            q[k] += __shfl_xor(q[k], off);
        }
    }
    const int lane = threadIdx.x & 63, w = threadIdx.x >> 6;
    if (lane < 4) {
        #pragma unroll
        for (int k = 0; k < 4; k++) {
            red[w][lane*4 + k]      = s[k];
            red[w][16 + lane*4 + k] = q[k];
        }
    }
    __syncthreads();
    if (threadIdx.x < 32) {
        float v = red[0][threadIdx.x] + red[1][threadIdx.x]
                + red[2][threadIdx.x] + red[3][threadIdx.x];
        atomicAdd(&stats[(threadIdx.x < 16) ? threadIdx.x : (48 + threadIdx.x)], v);
    }
}

// ---- MFMA implicit-GEMM 3x3 conv, one block (4 waves) per image ----
// FUSE: staging performs the PRECEDING bn_add (x=raw conv-B out, prev=residual):
//   act = relu(bn(x) + [PN? relu(bn(prev)) : prev]); written to resid AND LDS.
// Math identical to the separate bn_add pass (same f2bf point) -> bit-identical.
template<int CIN, int COUT, int HIN, int WIN, int ST, bool FUSE, bool PN>
__global__ __launch_bounds__(256, (COUT==16)?3:4) void conv_mfma(
    const unsigned short* __restrict__ src, const unsigned short* __restrict__ prev,
    unsigned short* __restrict__ resid,
    const unsigned short* __restrict__ wt,
    unsigned short* __restrict__ out, float* __restrict__ stats,
    const float* __restrict__ nstats, float ninvN,
    const float* __restrict__ pstats, float pinvN)
{
    constexpr int HO = HIN/ST, WO = WIN/ST, M = HO*WO, MT = M/16;
    constexpr int NT = COUT/16;
    constexpr int K  = 9*CIN;
    constexpr int S  = (K + 31)/32;
    constexpr int KPAD = S*32;
    constexpr int lgC  = (CIN==16)?4:(CIN==32)?5:6;
    constexpr int lgWI = (WIN==32)?5:(WIN==16)?4:3;
    constexpr int lgWO = (WO==32)?5:(WO==16)?4:3;
    constexpr int CMASK = CIN/8 - 1;
    constexpr int JITER = (NT==1)? MT/4 : (NT==2)? MT/2 : MT;
    static_assert(M*COUT <= CIN*HIN*WIN, "out_s fits in in_s");

    __shared__ unsigned short in_s[CIN*HIN*WIN];   // input, then output bounce
    __shared__ float red[128];
    __shared__ float nm[64], nv[64];
    __shared__ float pm_s[64], pv_s[64];
    __shared__ uint4 zq;

    const int tid = threadIdx.x;
    const int b   = blockIdx.x;

    if (tid == 0) { zq.x = 0; zq.y = 0; zq.z = 0; zq.w = 0; }
    if (nstats != nullptr && tid < CIN) {
        float m = nstats[tid]*ninvN;
        float v = fmaxf(nstats[64+tid]*ninvN - m*m, 0.f);
        nm[tid] = m; nv[tid] = rsqrtf(v + 1e-5f);
    }
    if (PN && tid < CIN) {
        float m = pstats[tid]*pinvN;
        float v = fmaxf(pstats[64+tid]*pinvN - m*m, 0.f);
        pm_s[tid] = m; pv_s[tid] = rsqrtf(v + 1e-5f);
    }
    __syncthreads();

    // ---- staging ----
    {
        const uint4* sb4 = (const uint4*)(src + (size_t)b*(HIN*WIN)*CIN);
        constexpr int NP4 = CIN*HIN*WIN/8;
        if (FUSE) {
            const uint4* pb4 = (const uint4*)(prev + (size_t)b*(HIN*WIN)*CIN);
            uint4* rb4 = (uint4*)(resid + (size_t)b*(HIN*WIN)*CIN);
            for (int i = tid; i < NP4; i += 256) {
                uint4 v = sb4[i];
                uint4 pw = pb4[i];
                int e0 = i << 3;
                int c0 = e0 & (CIN-1);
                int p  = e0 >> lgC;
                float f[8] = { bf2f(v.x & 0xffffu), bf2f(v.x >> 16),
                               bf2f(v.y & 0xffffu), bf2f(v.y >> 16),
                               bf2f(v.z & 0xffffu), bf2f(v.z >> 16),
                               bf2f(v.w & 0xffffu), bf2f(v.w >> 16) };
                float g[8] = { bf2f(pw.x & 0xffffu), bf2f(pw.x >> 16),
                               bf2f(pw.y & 0xffffu), bf2f(pw.y >> 16),
                               bf2f(pw.z & 0xffffu), bf2f(pw.z >> 16),
                               bf2f(pw.w & 0xffffu), bf2f(pw.w >> 16) };
                #pragma unroll
                for (int k = 0; k < 8; k++) {
                    int c = c0 + k;
                    float fx = (f[k] - nm[c])*nv[c];
                    float gv = g[k];
                    if (PN) gv = fmaxf((gv - pm_s[c])*pv_s[c], 0.f);
                    f[k] = fmaxf(fx + gv, 0.f);
                }
                uint4 o;
                o.x = (unsigned)f2bf(f[0]) | ((unsigned)f2bf(f[1]) << 16);
                o.y = (unsigned)f2bf(f[2]) | ((unsigned)f2bf(f[3]) << 16);
                o.z = (unsigned)f2bf(f[4]) | ((unsigned)f2bf(f[5]) << 16);
                o.w = (unsigned)f2bf(f[6]) | ((unsigned)f2bf(f[7]) << 16);
                rb4[i] = o;
                int csw = c0 ^ ((p & CMASK) << 3);
                *(uint4*)(in_s + (p << lgC) + csw) = o;
            }
        } else if (nstats == nullptr) {
            for (int i = tid; i < NP4; i += 256) {
                uint4 v = sb4[i];
                int e0 = i << 3;
                int c0 = e0 & (CIN-1);
                int p  = e0 >> lgC;
                int csw = c0 ^ ((p & CMASK) << 3);
                *(uint4*)(in_s + (p << lgC) + csw) = v;
            }
        } else {
            for (int i = tid; i < NP4; i += 256) {
                uint4 v = sb4[i];
                int e0 = i << 3;
                int c0 = e0 & (CIN-1);
                int p  = e0 >> lgC;
                float f[8] = { bf2f(v.x & 0xffffu), bf2f(v.x >> 16),
                               bf2f(v.y & 0xffffu), bf2f(v.y >> 16),
                               bf2f(v.z & 0xffffu), bf2f(v.z >> 16),
                               bf2f(v.w & 0xffffu), bf2f(v.w >> 16) };
                #pragma unroll
                for (int k = 0; k < 8; k++) {
                    int c = c0 + k;
                    f[k] = fmaxf((f[k] - nm[c])*nv[c], 0.f);
                }
                uint4 o;
                o.x = (unsigned)f2bf(f[0]) | ((unsigned)f2bf(f[1]) << 16);
                o.y = (unsigned)f2bf(f[2]) | ((unsigned)f2bf(f[3]) << 16);
                o.z = (unsigned)f2bf(f[4]) | ((unsigned)f2bf(f[5]) << 16);
                o.w = (unsigned)f2bf(f[6]) | ((unsigned)f2bf(f[7]) << 16);
                int csw = c0 ^ ((p & CMASK) << 3);
                *(uint4*)(in_s + (p << lgC) + csw) = o;
            }
        }
    }
    __syncthreads();

    const int w   = tid >> 6;
    const int ln  = tid & 63;
    const int l15 = ln & 15;
    const int q   = ln >> 4;

    int n0, mt0, step;
    if (NT == 1)      { n0 = 0;         mt0 = w;      step = 4; }
    else if (NT == 2) { n0 = (w&1)*16;  mt0 = w>>1;   step = 2; }
    else              { n0 = w*16;      mt0 = 0;      step = 1; }

    v8s Bf[S];
    {
        const unsigned short* wb = wt + (size_t)(n0 + l15)*KPAD + q*8;
        #pragma unroll
        for (int s = 0; s < S; s++)
            Bf[s] = *(const v8s*)(wb + 32*s);
    }

    int dh1s[S], dw1s[S];
    int c0q = (CIN==16) ? ((q & 1) << 3) : (q << 3);
    if (CIN == 16) {
        int tq = q >> 1;
        #pragma unroll
        for (int s = 0; s < S; s++) {
            int tap = 2*s + tq;
            int dh = (tap*11) >> 5;
            int dw = tap - 3*dh;
            dh1s[s] = (tap >= 9) ? -1000 : (dh - 1);
            dw1s[s] = dw - 1;
        }
    }

    v4f acc[JITER];
    #pragma unroll
    for (int j = 0; j < JITER; j++) acc[j] = v4f{0.f,0.f,0.f,0.f};

    #pragma unroll
    for (int j = 0; j < JITER; j++) {
        const int mt  = mt0 + j*step;
        const int p   = mt*16 + l15;
        const int ihb = (p >> lgWO) * ST;
        const int iwb = (p & (WO-1)) * ST;
        #pragma unroll
        for (int s = 0; s < S; s++) {
            int dh1, dw1, c0s;
            if (CIN == 16) { dh1 = dh1s[s]; dw1 = dw1s[s]; c0s = c0q; }
            else {
                const int tap = (CIN == 32) ? s : (s >> 1);
                dh1 = tap/3 - 1; dw1 = tap%3 - 1;
                c0s = c0q + ((CIN == 64) ? ((s & 1) << 5) : 0);
            }
            int ih = ihb + dh1, iw = iwb + dw1;
            bool valid = ((unsigned)ih < (unsigned)HIN) && ((unsigned)iw < (unsigned)WIN);
            int pp  = (ih << lgWI) + iw;
            int csw = c0s ^ ((pp & CMASK) << 3);
            int eoff = (pp << lgC) + csw;
            const v8s* ap = valid ? (const v8s*)(in_s + eoff) : (const v8s*)&zq;
            v8s Af = *ap;
            acc[j] = __builtin_amdgcn_mfma_f32_16x16x32_bf16(Af, Bf[s], acc[j], 0, 0, 0);
        }
    }
    __syncthreads();   // all in_s reads complete -> reuse as output bounce

    unsigned short* out_s = in_s;
    float sa = 0.f, qa = 0.f;
    #pragma unroll
    for (int j = 0; j < JITER; j++) {
        const int mt = mt0 + j*step;
        #pragma unroll
        for (int r2 = 0; r2 < 4; r2++) {
            float v = acc[j][r2];
            out_s[(mt*16 + q*4 + r2)*COUT + n0 + l15] = f2bf(v);
            sa += v; qa += v*v;
        }
    }
    __syncthreads();

    {
        constexpr int NIT = (M*COUT/8)/256;
        uint4* ob4 = (uint4*)(out + (size_t)b*M*COUT);
        const uint4* os4 = (const uint4*)in_s;
        #pragma unroll
        for (int it = 0; it < NIT; it++)
            ob4[it*256 + tid] = os4[it*256 + tid];
    }

    sa += __shfl_xor(sa, 16); sa += __shfl_xor(sa, 32);
    qa += __shfl_xor(qa, 16); qa += __shfl_xor(qa, 32);
    if (q == 0) {
        red[(w*16 + l15)*2]     = sa;
        red[(w*16 + l15)*2 + 1] = qa;
    }
    __syncthreads();
    if (tid < COUT) {
        float S2, Q2;
        if (NT == 1) {
            S2 = red[tid*2] + red[(16+tid)*2] + red[(32+tid)*2] + red[(48+tid)*2];
            Q2 = red[tid*2+1] + red[(16+tid)*2+1] + red[(32+tid)*2+1] + red[(48+tid)*2+1];
        } else if (NT == 2) {
            int w0 = tid >> 4, cl = tid & 15;
            S2 = red[((w0*16)+cl)*2]     + red[(((w0+2)*16)+cl)*2];
            Q2 = red[((w0*16)+cl)*2 + 1] + red[(((w0+2)*16)+cl)*2 + 1];
        } else {
            int w0 = tid >> 4, cl = tid & 15;
            S2 = red[((w0*16)+cl)*2];
            Q2 = red[((w0*16)+cl)*2 + 1];
        }
        atomicAdd(&stats[tid],      S2);
        atomicAdd(&stats[64 + tid], Q2);
    }
}

// y = relu(bn(x) + shortcut(prev)); all NHWC bf16; 4 elements/thread
template<int lgC, int lgHW, int lgW, int ST, bool PN>
__global__ __launch_bounds__(256) void bn_add_relu_nhwc(
    const unsigned short* __restrict__ x,
    const unsigned short* __restrict__ prev,
    unsigned short* __restrict__ outp,
    const float* __restrict__ stats, const float* __restrict__ pstats,
    int prevC, int padF, float invN, float pinvN, int n4)
{
    int i4 = blockIdx.x*256 + threadIdx.x;
    if (i4 >= n4) return;
    constexpr int C = 1<<lgC, HW = 1<<lgHW, W = 1<<lgW;
    const int i  = i4*4;
    const int c0 = i & (C-1);
    const int p  = (i >> lgC) & (HW-1);
    const int b  = i >> (lgC + lgHW);

    uint2 xv = ((const uint2*)x)[i4];
    float xf[4] = { bf2f(xv.x & 0xffffu), bf2f(xv.x >> 16),
                    bf2f(xv.y & 0xffffu), bf2f(xv.y >> 16) };
    float sc[4];
    if (ST == 1) {
        uint2 pv = ((const uint2*)prev)[i4];
        sc[0] = bf2f(pv.x & 0xffffu); sc[1] = bf2f(pv.x >> 16);
        sc[2] = bf2f(pv.y & 0xffffu); sc[3] = bf2f(pv.y >> 16);
        if (PN) {
            #pragma unroll
            for (int k = 0; k < 4; k++) {
                int c = c0 + k;
                float pm = pstats[c]*pinvN;
                float pvv = fmaxf(pstats[64+c]*pinvN - pm*pm, 0.f);
                sc[k] = fmaxf((sc[k] - pm)*rsqrtf(pvv + 1e-5f), 0.f);
            }
        }
    } else {
        int h = p >> lgW, wq = p & (W-1);
        int pp = (h << (lgW+2)) + 2*wq;
        #pragma unroll
        for (int k = 0; k < 4; k++) {
            int pc = c0 + k - padF;
            sc[k] = (pc >= 0 && pc < prevC)
                  ? bf2f((unsigned int)prev[((size_t)b*(HW*4) + pp)*prevC + pc]) : 0.f;
        }
    }
    float o[4];
    #pragma unroll
    for (int k = 0; k < 4; k++) {
        int c = c0 + k;
        float m = stats[c]*invN;
        float v = fmaxf(stats[64+c]*invN - m*m, 0.f);
        o[k] = fmaxf((xf[k]-m)*rsqrtf(v + 1e-5f) + sc[k], 0.f);
    }
    uint2 ov;
    ov.x = (unsigned)f2bf(o[0]) | ((unsigned)f2bf(o[1]) << 16);
    ov.y = (unsigned)f2bf(o[2]) | ((unsigned)f2bf(o[3]) << 16);
    ((uint2*)outp)[i4] = ov;
}

__device__ inline void stf(float* p, float v){ *p = v; }
__device__ inline void stf(__hip_bfloat16* p, float v){ *p = __float2bfloat16(v); }

// mean over 8x8 spatial (NHWC bf16) -> (B,64); out = feat @ Wfc^T + bfc -> (B,10)
template<typename T>
__global__ void poolfc_kernel(const unsigned short* __restrict__ in,
    const T* __restrict__ Wfc, const T* __restrict__ bfc,
    T* __restrict__ out, const int* flag, int want)
{
    if (flag_skip(flag, want)) return;
    int b = blockIdx.x;
    int c = threadIdx.x; // 64 threads
    float s = 0.f;
    #pragma unroll
    for (int p = 0; p < 64; p++) s += bf2f((unsigned int)in[((size_t)b*64 + p)*64 + c]);
    __shared__ float feat[64];
    feat[c] = s * (1.f/64.f);
    __syncthreads();
    if (c < 10) {
        float o = ldf(bfc + c);
        for (int k = 0; k < 64; k++)
            o += feat[k] * ldf(Wfc + c*64 + k);
        stf(out + b*10 + c, o);
    }
}

extern "C" void kernel_launch(void* const* d_in, const int* in_sizes, int n_in,
                              void* d_out, int out_size, void* d_ws, size_t ws_size,
                              hipStream_t stream)
{
    char* ws = (char*)d_ws;
    float* wflat = (float*)(ws);                            // DTOT fp32
    float* stats = (float*)(ws + 1114112);                  // 19 x 256 fp32
    int*   flag  = (int*)  (ws + 1146880);
    unsigned short* WT = (unsigned short*)(ws + 1179648);   // 269312 bf16
    unsigned short* curA = (unsigned short*)(ws + 1720320);               // 33.5MB
    unsigned short* curB = (unsigned short*)(ws + 1720320 + 33554432ULL); // 33.5MB (l0 raw)
    unsigned short* f1   = (unsigned short*)(ws + 1720320 + 67108864ULL);
    unsigned short* f2   = (unsigned short*)(ws + 1720320 + 100663296ULL);

    hipMemsetAsync(stats, 0, 32768, stream);
    detect_kernel<<<1, 256, 0, stream>>>((const unsigned short*)d_in[0], flag);

    wflat_kernel<__hip_bfloat16><<<(DTOT+255)/256, 256, 0, stream>>>(
        (const __hip_bfloat16*)d_in[1], (const __hip_bfloat16*)d_in[2],
        (const __hip_bfloat16*)d_in[3], wflat, DTOT, flag, 1);
    wflat_kernel<float><<<(DTOT+255)/256, 256, 0, stream>>>(
        (const float*)d_in[1], (const float*)d_in[2],
        (const float*)d_in[3], wflat, DTOT, flag, 0);

    {
        dim3 g(3, 64, 19);
        wprep_kernel<<<g, 192, 0, stream>>>(wflat, WT);
    }

    static const int WTOFF[NLAYER] = {0,0,2560,5120,7680,10240,12800,15360,20480,29696,
        38912,48128,57344,66560,84992,121856,158720,195584,232448};
    const float iN32 = 1.f/1048576.f;   // B*32*32
    const float iN16 = 1.f/262144.f;    // B*16*16
    const float iN8  = 1.f/65536.f;     // B*8*8

    // ---- layer 0 ----
    conv_l0<__hip_bfloat16><<<2*BATCH,512,0,stream>>>(
        (const __hip_bfloat16*)d_in[0], wflat, curB, flag, 1);
    conv_l0<float><<<2*BATCH,512,0,stream>>>(
        (const float*)d_in[0], wflat, curB, flag, 0);
    stats16_kernel<<<512,256,0,stream>>>(curB, stats, 4194304);

    // b0: conv-A(l1) reads l0 raw w/ nstats; conv-B(l2)
    conv_mfma<16,16,32,32,1,false,false><<<BATCH,256,0,stream>>>(
        curB, nullptr, nullptr, WT + WTOFF[1], f1, stats + 1*256, stats, iN32, nullptr, 0.f);
    conv_mfma<16,16,32,32,1,false,false><<<BATCH,256,0,stream>>>(
        f1, nullptr, nullptr, WT + WTOFF[2], f2, stats + 2*256, stats + 1*256, iN32, nullptr, 0.f);
    // b1: fused bn_add(b0) [PN=l0 stats] into conv-A(l3); resid -> curA
    conv_mfma<16,16,32,32,1,true,true><<<BATCH,256,0,stream>>>(
        f2, curB, curA, WT + WTOFF[3], f1, stats + 3*256, stats + 2*256, iN32, stats, iN32);
    conv_mfma<16,16,32,32,1,false,false><<<BATCH,256,0,stream>>>(
        f1, nullptr, nullptr, WT + WTOFF[4], f2, stats + 4*256, stats + 3*256, iN32, nullptr, 0.f);
    // b2: fused bn_add(b1) into conv-A(l5); resid -> curB
    conv_mfma<16,16,32,32,1,true,false><<<BATCH,256,0,stream>>>(
        f2, curA, curB, WT + WTOFF[5], f1, stats + 5*256, stats + 4*256, iN32, nullptr, 0.f);
    conv_mfma<16,16,32,32,1,false,false><<<BATCH,256,0,stream>>>(
        f1, nullptr, nullptr, WT + WTOFF[6], f2, stats + 6*256, stats + 5*256, iN32, nullptr, 0.f);
    // b3: fused bn_add(b2) into stride-2 conv-A(l7); resid -> curA (32²,16ch)
    conv_mfma<16,32,32,32,2,true,false><<<BATCH,256,0,stream>>>(
        f2, curB, curA, WT + WTOFF[7], f1, stats + 7*256, stats + 6*256, iN32, nullptr, 0.f);
    conv_mfma<32,32,16,16,1,false,false><<<BATCH,256,0,stream>>>(
        f1, nullptr, nullptr, WT + WTOFF[8], f2, stats + 8*256, stats + 7*256, iN16, nullptr, 0.f);
    bn_add_relu_nhwc<5,8,4,2,false><<<8192,256,0,stream>>>(
        f2, curA, curB, stats + 8*256, nullptr, 16, 8, iN16, 0.f, 2097152);
    // b4: conv-A(l9) plain reads curB
    conv_mfma<32,32,16,16,1,false,false><<<BATCH,256,0,stream>>>(
        curB, nullptr, nullptr, WT + WTOFF[9], f1, stats + 9*256, nullptr, 0.f, nullptr, 0.f);
    conv_mfma<32,32,16,16,1,false,false><<<BATCH,256,0,stream>>>(
        f1, nullptr, nullptr, WT + WTOFF[10], f2, stats + 10*256, stats + 9*256, iN16, nullptr, 0.f);
    // b5: fused bn_add(b4) into conv-A(l11); resid -> curA
    conv_mfma<32,32,16,16,1,true,false><<<BATCH,256,0,stream>>>(
        f2, curB, curA, WT + WTOFF[11], f1, stats + 11*256, stats + 10*256, iN16, nullptr, 0.f);
    conv_mfma<32,32,16,16,1,false,false><<<BATCH,256,0,stream>>>(
        f1, nullptr, nullptr, WT + WTOFF[12], f2, stats + 12*256, stats + 11*256, iN16, nullptr, 0.f);
    // b6: fused bn_add(b5) into stride-2 conv-A(l13); resid -> curB (16²,32ch)
    conv_mfma<32,64,16,16,2,true,false><<<BATCH,256,0,stream>>>(
        f2, curA, curB, WT + WTOFF[13], f1, stats + 13*256, stats + 12*256, iN16, nullptr, 0.f);
    conv_mfma<64,64,8,8,1,false,false><<<BATCH,256,0,stream>>>(
        f1, nullptr, nullptr, WT + WTOFF[14], f2, stats + 14*256, stats + 13*256, iN8, nullptr, 0.f);
    bn_add_relu_nhwc<6,6,3,2,false><<<4096,256,0,stream>>>(
        f2, curB, curA, stats + 14*256, nullptr, 32, 16, iN8, 0.f, 1048576);
    // b7: conv-A(l15) plain reads curA
    conv_mfma<64,64,8,8,1,false,false><<<BATCH,256,0,stream>>>(
        curA, nullptr, nullptr, WT + WTOFF[15], f1, stats + 15*256, nullptr, 0.f, nullptr, 0.f);
    conv_mfma<64,64,8,8,1,false,false><<<BATCH,256,0,stream>>>(
        f1, nullptr, nullptr, WT + WTOFF[16], f2, stats + 16*256, stats + 15*256, iN8, nullptr, 0.f);
    // b8: fused bn_add(b7) into conv-A(l17); resid -> curB
    conv_mfma<64,64,8,8,1,true,false><<<BATCH,256,0,stream>>>(
        f2, curA, curB, WT + WTOFF[17], f1, stats + 17*256, stats + 16*256, iN8, nullptr, 0.f);
    conv_mfma<64,64,8,8,1,false,false><<<BATCH,256,0,stream>>>(
        f1, nullptr, nullptr, WT + WTOFF[18], f2, stats + 18*256, stats + 17*256, iN8, nullptr, 0.f);
    bn_add_relu_nhwc<6,6,3,1,false><<<4096,256,0,stream>>>(
        f2, curB, curA, stats + 18*256, nullptr, 64, 0, iN8, 0.f, 1048576);

    poolfc_kernel<__hip_bfloat16><<<BATCH, 64, 0, stream>>>(
        curA, (const __hip_bfloat16*)d_in[4], (const __hip_bfloat16*)d_in[5],
        (__hip_bfloat16*)d_out, flag, 1);
    poolfc_kernel<float><<<BATCH, 64, 0, stream>>>(
        curA, (const float*)d_in[4], (const float*)d_in[5],
        (float*)d_out, flag, 0);
}

// Round 17
// 724.909 us; speedup vs baseline: 1.0746x; 1.0045x over previous
//
#include <hip/hip_runtime.h>
#include <hip/hip_bf16.h>

#define BATCH 1024
#define NLAYER 19
#define DTOT 267696

typedef __attribute__((ext_vector_type(8))) short v8s;
typedef __attribute__((ext_vector_type(4))) float v4f;

__device__ inline float ldf(const float* p){ return *p; }
__device__ inline float ldf(const __hip_bfloat16* p){ return __bfloat162float(*p); }

__device__ inline unsigned short f2bf(float x){
    __hip_bfloat16 h = __float2bfloat16(x);
    return *reinterpret_cast<unsigned short*>(&h);
}
__device__ inline float bf2f(unsigned int u){
    return __uint_as_float(u << 16);
}

// ---- dtype detector: flag=1 if inputs bf16, 0 if f32 ----
__global__ void detect_kernel(const unsigned short* __restrict__ xraw, int* __restrict__ flag)
{
    __shared__ int bad;
    if (threadIdx.x == 0) bad = 0;
    __syncthreads();
    int lbad = 0;
    for (int i = threadIdx.x; i < 4096; i += 256) {
        unsigned e = (xraw[i] >> 7) & 0xFF;
        if (e >= 147) lbad++;
    }
    if (lbad) atomicAdd(&bad, lbad);
    __syncthreads();
    if (threadIdx.x == 0) *flag = (bad == 0) ? 1 : 0;
}

__device__ inline bool flag_skip(const int* flag, int want)
{
    if (flag == nullptr) return false;
    return (*(volatile const int*)flag) != want;
}

// w_flat = origin + new_param @ P
template<typename T>
__global__ void wflat_kernel(const T* __restrict__ origin,
                             const T* __restrict__ P,
                             const T* __restrict__ npar,
                             float* __restrict__ wout, int D,
                             const int* flag, int want)
{
    if (flag_skip(flag, want)) return;
    int d = blockIdx.x*256 + threadIdx.x;
    if (d >= D) return;
    float acc = ldf(origin + d);
    #pragma unroll 8
    for (int k = 0; k < 40; k++)
        acc += ldf(npar + k) * ldf(P + (long long)k*D + d);
    wout[d] = acc;
}

// ---- weight transform: wflat (OIHW fp32) -> W_T[l][cout][kpad] bf16, k = tap*Cin+ci
__global__ void wprep_kernel(const float* __restrict__ wflat, unsigned short* __restrict__ WT)
{
    static const int CINA[19]  = {3,16,16,16,16,16,16,16,32,32,32,32,32,32,64,64,64,64,64};
    static const int COUTA[19] = {16,16,16,16,16,16,16,32,32,32,32,32,32,64,64,64,64,64,64};
    static const int LGCA[19]  = {0,4,4,4,4,4,4,4,5,5,5,5,5,5,6,6,6,6,6};
    static const int KPADA[19] = {0,160,160,160,160,160,160,160,288,288,288,288,288,288,576,576,576,576,576};
    static const int WOFFA[19] = {0,432,2736,5040,7344,9648,11952,14256,18864,
        28080,37296,46512,55728,64944,83376,120240,157104,193968,230832};
    static const int WTOFFA[19]= {0,0,2560,5120,7680,10240,12800,15360,20480,29696,
        38912,48128,57344,66560,84992,121856,158720,195584,232448};
    int l = blockIdx.z;
    if (l == 0) return;
    int co = blockIdx.y;
    if (co >= COUTA[l]) return;
    int kp = blockIdx.x*192 + threadIdx.x;
    if (kp >= KPADA[l]) return;
    int cin = CINA[l];
    float v = 0.f;
    if (kp < 9*cin) {
        int tap = kp >> LGCA[l];
        int ci  = kp & (cin - 1);
        v = wflat[WOFFA[l] + (co*cin + ci)*9 + tap];
    }
    WT[WTOFFA[l] + co*KPADA[l] + kp] = f2bf(v);
}

__device__ inline void ldpair(const float* base, int p, float& x0, float& x1){
    const float2 v = ((const float2*)base)[p];
    x0 = v.x; x1 = v.y;
}
__device__ inline void ldpair(const __hip_bfloat16* base, int p, float& x0, float& x1){
    unsigned u = ((const unsigned int*)base)[p];
    x0 = __uint_as_float(u << 16);
    x1 = __uint_as_float(u & 0xffff0000u);
}

// ---- layer 0: direct conv (Cin=3), NCHW input -> NHWC bf16 raw ----
template<typename T>
__global__ __launch_bounds__(512) void conv_l0(
    const T* __restrict__ in, const float* __restrict__ wt,
    unsigned short* __restrict__ out,
    const int* flag, int want)
{
    if (flag_skip(flag, want)) return;
    constexpr int WP = 38, W2 = 19;
    __shared__ uint2 smem2[2048];
    __shared__ unsigned int in_su[3*18*W2];
    __shared__ float w_s[432];

    const int tid  = threadIdx.x;
    const int b    = blockIdx.x >> 1;
    const int half = blockIdx.x & 1;
    const int row0 = half*16 - 1;

    {
        const T* inb = in + (size_t)b*3072;
        for (int i = tid; i < 864; i += 512) {
            int w2 = i & 15, lr = (i >> 4) % 18, c = i / 288;
            int ih = row0 + lr;
            unsigned int pk = 0u;
            if ((unsigned)ih < 32u) {
                float x0, x1;
                ldpair(inb, (c*32 + ih)*16 + w2, x0, x1);
                pk = (unsigned int)f2bf(x0) | ((unsigned int)f2bf(x1) << 16);
            }
            in_su[(c*18 + lr)*W2 + 1 + w2] = pk;
        }
        unsigned short* in_ss = (unsigned short*)in_su;
        for (int i = tid; i < 54; i += 512) {
            in_ss[i*WP + 1]  = 0;
            in_ss[i*WP + 34] = 0;
        }
        for (int i = tid; i < 432; i += 512) w_s[i] = wt[i];
    }
    __syncthreads();

    const int r   = tid >> 5;
    const int col = tid & 31;

    float acc[16];
    #pragma unroll
    for (int c = 0; c < 16; c++) acc[c] = 0.f;

    #pragma unroll
    for (int ci = 0; ci < 3; ci++) {
        #pragma unroll
        for (int kh = 0; kh < 3; kh++) {
            const unsigned int* up = in_su + (ci*18 + r + kh)*W2 + ((col+1) >> 1);
            unsigned int u0 = up[0], u1 = up[1];
            bool odd = (col & 1);
            float s1 = odd ? bf2f(u0 & 0xffffu) : bf2f(u0 >> 16);
            float s2 = odd ? bf2f(u0 >> 16)     : bf2f(u1 & 0xffffu);
            float s3 = odd ? bf2f(u1 & 0xffffu) : bf2f(u1 >> 16);
            const float* wp = w_s + ci*9 + kh*3;
            #pragma unroll
            for (int co = 0; co < 16; co++) {
                acc[co] += s1*wp[co*27+0] + s2*wp[co*27+1] + s3*wp[co*27+2];
            }
        }
    }

    #pragma unroll
    for (int j = 0; j < 4; j++) {
        uint2 v;
        v.x = (unsigned)f2bf(acc[4*j+0]) | ((unsigned)f2bf(acc[4*j+1]) << 16);
        v.y = (unsigned)f2bf(acc[4*j+2]) | ((unsigned)f2bf(acc[4*j+3]) << 16);
        smem2[tid*4 + (j ^ (tid & 3))] = v;
    }
    __syncthreads();
    {
        uint2* ob = (uint2*)(out + (size_t)b*16384 + half*8192);
        #pragma unroll
        for (int it = 0; it < 4; it++) {
            int s = it*512 + tid;
            int phys = (s & ~3) | ((s & 3) ^ ((s >> 2) & 3));
            ob[s] = smem2[phys];
        }
    }
}

// ---- per-channel sum/sumsq over NHWC bf16, C=16; 32 atomics/block ----
__global__ __launch_bounds__(256) void stats16_kernel(
    const unsigned short* __restrict__ x, float* __restrict__ stats, int n4)
{
    __shared__ float red[4][32];
    int t = blockIdx.x*256 + threadIdx.x;
    const int stride = gridDim.x*256;
    float s[4] = {0,0,0,0}, q[4] = {0,0,0,0};
    for (int i = t; i < n4; i += stride) {
        uint2 v = ((const uint2*)x)[i];
        float f0 = bf2f(v.x & 0xffffu), f1 = bf2f(v.x >> 16);
        float f2_ = bf2f(v.y & 0xffffu), f3 = bf2f(v.y >> 16);
        s[0] += f0; q[0] += f0*f0;
        s[1] += f1; q[1] += f1*f1;
        s[2] += f2_; q[2] += f2_*f2_;
        s[3] += f3; q[3] += f3*f3;
    }
    #pragma unroll
    for (int off = 4; off < 64; off <<= 1) {
        #pragma unroll
        for (int k = 0; k < 4; k++) {
            s[k] += __shfl_xor(s[k], off);
            q[k] += __shfl_xor(q[k], off);
        }
    }
    const int lane = threadIdx.x & 63, w = threadIdx.x >> 6;
    if (lane < 4) {
        #pragma unroll
        for (int k = 0; k < 4; k++) {
            red[w][lane*4 + k]      = s[k];
            red[w][16 + lane*4 + k] = q[k];
        }
    }
    __syncthreads();
    if (threadIdx.x < 32) {
        float v = red[0][threadIdx.x] + red[1][threadIdx.x]
                + red[2][threadIdx.x] + red[3][threadIdx.x];
        atomicAdd(&stats[(threadIdx.x < 16) ? threadIdx.x : (48 + threadIdx.x)], v);
    }
}

// ---- MFMA implicit-GEMM 3x3 conv, one block (4 waves) per image ----
// launch_bounds(256,4): 4 blocks/CU -> all 1024 blocks resident in one round.
// (VGPR budget ~114 at JITER=16; spill tripwire = WRITE_SIZE balloon.)
template<int CIN, int COUT, int HIN, int WIN, int ST, bool FUSE, bool PN>
__global__ __launch_bounds__(256, 4) void conv_mfma(
    const unsigned short* __restrict__ src, const unsigned short* __restrict__ prev,
    unsigned short* __restrict__ resid,
    const unsigned short* __restrict__ wt,
    unsigned short* __restrict__ out, float* __restrict__ stats,
    const float* __restrict__ nstats, float ninvN,
    const float* __restrict__ pstats, float pinvN)
{
    constexpr int HO = HIN/ST, WO = WIN/ST, M = HO*WO, MT = M/16;
    constexpr int NT = COUT/16;
    constexpr int K  = 9*CIN;
    constexpr int S  = (K + 31)/32;
    constexpr int KPAD = S*32;
    constexpr int lgC  = (CIN==16)?4:(CIN==32)?5:6;
    constexpr int lgWI = (WIN==32)?5:(WIN==16)?4:3;
    constexpr int lgWO = (WO==32)?5:(WO==16)?4:3;
    constexpr int CMASK = CIN/8 - 1;
    constexpr int JITER = (NT==1)? MT/4 : (NT==2)? MT/2 : MT;
    static_assert(M*COUT <= CIN*HIN*WIN, "out_s fits in in_s");

    __shared__ unsigned short in_s[CIN*HIN*WIN];   // input, then output bounce
    __shared__ float red[128];
    __shared__ float nm[64], nv[64];
    __shared__ float pm_s[64], pv_s[64];
    __shared__ uint4 zq;

    const int tid = threadIdx.x;
    const int b   = blockIdx.x;

    if (tid == 0) { zq.x = 0; zq.y = 0; zq.z = 0; zq.w = 0; }
    if (nstats != nullptr && tid < CIN) {
        float m = nstats[tid]*ninvN;
        float v = fmaxf(nstats[64+tid]*ninvN - m*m, 0.f);
        nm[tid] = m; nv[tid] = rsqrtf(v + 1e-5f);
    }
    if (PN && tid < CIN) {
        float m = pstats[tid]*pinvN;
        float v = fmaxf(pstats[64+tid]*pinvN - m*m, 0.f);
        pm_s[tid] = m; pv_s[tid] = rsqrtf(v + 1e-5f);
    }
    __syncthreads();

    // ---- staging ----
    {
        const uint4* sb4 = (const uint4*)(src + (size_t)b*(HIN*WIN)*CIN);
        constexpr int NP4 = CIN*HIN*WIN/8;
        if (FUSE) {
            const uint4* pb4 = (const uint4*)(prev + (size_t)b*(HIN*WIN)*CIN);
            uint4* rb4 = (uint4*)(resid + (size_t)b*(HIN*WIN)*CIN);
            for (int i = tid; i < NP4; i += 256) {
                uint4 v = sb4[i];
                uint4 pw = pb4[i];
                int e0 = i << 3;
                int c0 = e0 & (CIN-1);
                int p  = e0 >> lgC;
                float f[8] = { bf2f(v.x & 0xffffu), bf2f(v.x >> 16),
                               bf2f(v.y & 0xffffu), bf2f(v.y >> 16),
                               bf2f(v.z & 0xffffu), bf2f(v.z >> 16),
                               bf2f(v.w & 0xffffu), bf2f(v.w >> 16) };
                float g[8] = { bf2f(pw.x & 0xffffu), bf2f(pw.x >> 16),
                               bf2f(pw.y & 0xffffu), bf2f(pw.y >> 16),
                               bf2f(pw.z & 0xffffu), bf2f(pw.z >> 16),
                               bf2f(pw.w & 0xffffu), bf2f(pw.w >> 16) };
                #pragma unroll
                for (int k = 0; k < 8; k++) {
                    int c = c0 + k;
                    float fx = (f[k] - nm[c])*nv[c];
                    float gv = g[k];
                    if (PN) gv = fmaxf((gv - pm_s[c])*pv_s[c], 0.f);
                    f[k] = fmaxf(fx + gv, 0.f);
                }
                uint4 o;
                o.x = (unsigned)f2bf(f[0]) | ((unsigned)f2bf(f[1]) << 16);
                o.y = (unsigned)f2bf(f[2]) | ((unsigned)f2bf(f[3]) << 16);
                o.z = (unsigned)f2bf(f[4]) | ((unsigned)f2bf(f[5]) << 16);
                o.w = (unsigned)f2bf(f[6]) | ((unsigned)f2bf(f[7]) << 16);
                rb4[i] = o;
                int csw = c0 ^ ((p & CMASK) << 3);
                *(uint4*)(in_s + (p << lgC) + csw) = o;
            }
        } else if (nstats == nullptr) {
            for (int i = tid; i < NP4; i += 256) {
                uint4 v = sb4[i];
                int e0 = i << 3;
                int c0 = e0 & (CIN-1);
                int p  = e0 >> lgC;
                int csw = c0 ^ ((p & CMASK) << 3);
                *(uint4*)(in_s + (p << lgC) + csw) = v;
            }
        } else {
            for (int i = tid; i < NP4; i += 256) {
                uint4 v = sb4[i];
                int e0 = i << 3;
                int c0 = e0 & (CIN-1);
                int p  = e0 >> lgC;
                float f[8] = { bf2f(v.x & 0xffffu), bf2f(v.x >> 16),
                               bf2f(v.y & 0xffffu), bf2f(v.y >> 16),
                               bf2f(v.z & 0xffffu), bf2f(v.z >> 16),
                               bf2f(v.w & 0xffffu), bf2f(v.w >> 16) };
                #pragma unroll
                for (int k = 0; k < 8; k++) {
                    int c = c0 + k;
                    f[k] = fmaxf((f[k] - nm[c])*nv[c], 0.f);
                }
                uint4 o;
                o.x = (unsigned)f2bf(f[0]) | ((unsigned)f2bf(f[1]) << 16);
                o.y = (unsigned)f2bf(f[2]) | ((unsigned)f2bf(f[3]) << 16);
                o.z = (unsigned)f2bf(f[4]) | ((unsigned)f2bf(f[5]) << 16);
                o.w = (unsigned)f2bf(f[6]) | ((unsigned)f2bf(f[7]) << 16);
                int csw = c0 ^ ((p & CMASK) << 3);
                *(uint4*)(in_s + (p << lgC) + csw) = o;
            }
        }
    }
    __syncthreads();

    const int w   = tid >> 6;
    const int ln  = tid & 63;
    const int l15 = ln & 15;
    const int q   = ln >> 4;

    int n0, mt0, step;
    if (NT == 1)      { n0 = 0;         mt0 = w;      step = 4; }
    else if (NT == 2) { n0 = (w&1)*16;  mt0 = w>>1;   step = 2; }
    else              { n0 = w*16;      mt0 = 0;      step = 1; }

    v8s Bf[S];
    {
        const unsigned short* wb = wt + (size_t)(n0 + l15)*KPAD + q*8;
        #pragma unroll
        for (int s = 0; s < S; s++)
            Bf[s] = *(const v8s*)(wb + 32*s);
    }

    int dh1s[S], dw1s[S];
    int c0q = (CIN==16) ? ((q & 1) << 3) : (q << 3);
    if (CIN == 16) {
        int tq = q >> 1;
        #pragma unroll
        for (int s = 0; s < S; s++) {
            int tap = 2*s + tq;
            int dh = (tap*11) >> 5;
            int dw = tap - 3*dh;
            dh1s[s] = (tap >= 9) ? -1000 : (dh - 1);
            dw1s[s] = dw - 1;
        }
    }

    v4f acc[JITER];
    #pragma unroll
    for (int j = 0; j < JITER; j++) acc[j] = v4f{0.f,0.f,0.f,0.f};

    #pragma unroll
    for (int j = 0; j < JITER; j++) {
        const int mt  = mt0 + j*step;
        const int p   = mt*16 + l15;
        const int ihb = (p >> lgWO) * ST;
        const int iwb = (p & (WO-1)) * ST;
        #pragma unroll
        for (int s = 0; s < S; s++) {
            int dh1, dw1, c0s;
            if (CIN == 16) { dh1 = dh1s[s]; dw1 = dw1s[s]; c0s = c0q; }
            else {
                const int tap = (CIN == 32) ? s : (s >> 1);
                dh1 = tap/3 - 1; dw1 = tap%3 - 1;
                c0s = c0q + ((CIN == 64) ? ((s & 1) << 5) : 0);
            }
            int ih = ihb + dh1, iw = iwb + dw1;
            bool valid = ((unsigned)ih < (unsigned)HIN) && ((unsigned)iw < (unsigned)WIN);
            int pp  = (ih << lgWI) + iw;
            int csw = c0s ^ ((pp & CMASK) << 3);
            int eoff = (pp << lgC) + csw;
            const v8s* ap = valid ? (const v8s*)(in_s + eoff) : (const v8s*)&zq;
            v8s Af = *ap;
            acc[j] = __builtin_amdgcn_mfma_f32_16x16x32_bf16(Af, Bf[s], acc[j], 0, 0, 0);
        }
    }
    __syncthreads();   // all in_s reads complete -> reuse as output bounce

    unsigned short* out_s = in_s;
    float sa = 0.f, qa = 0.f;
    #pragma unroll
    for (int j = 0; j < JITER; j++) {
        const int mt = mt0 + j*step;
        #pragma unroll
        for (int r2 = 0; r2 < 4; r2++) {
            float v = acc[j][r2];
            out_s[(mt*16 + q*4 + r2)*COUT + n0 + l15] = f2bf(v);
            sa += v; qa += v*v;
        }
    }
    __syncthreads();

    {
        constexpr int NIT = (M*COUT/8)/256;
        uint4* ob4 = (uint4*)(out + (size_t)b*M*COUT);
        const uint4* os4 = (const uint4*)in_s;
        #pragma unroll
        for (int it = 0; it < NIT; it++)
            ob4[it*256 + tid] = os4[it*256 + tid];
    }

    sa += __shfl_xor(sa, 16); sa += __shfl_xor(sa, 32);
    qa += __shfl_xor(qa, 16); qa += __shfl_xor(qa, 32);
    if (q == 0) {
        red[(w*16 + l15)*2]     = sa;
        red[(w*16 + l15)*2 + 1] = qa;
    }
    __syncthreads();
    if (tid < COUT) {
        float S2, Q2;
        if (NT == 1) {
            S2 = red[tid*2] + red[(16+tid)*2] + red[(32+tid)*2] + red[(48+tid)*2];
            Q2 = red[tid*2+1] + red[(16+tid)*2+1] + red[(32+tid)*2+1] + red[(48+tid)*2+1];
        } else if (NT == 2) {
            int w0 = tid >> 4, cl = tid & 15;
            S2 = red[((w0*16)+cl)*2]     + red[(((w0+2)*16)+cl)*2];
            Q2 = red[((w0*16)+cl)*2 + 1] + red[(((w0+2)*16)+cl)*2 + 1];
        } else {
            int w0 = tid >> 4, cl = tid & 15;
            S2 = red[((w0*16)+cl)*2];
            Q2 = red[((w0*16)+cl)*2 + 1];
        }
        atomicAdd(&stats[tid],      S2);
        atomicAdd(&stats[64 + tid], Q2);
    }
}

// y = relu(bn(x) + shortcut(prev)); all NHWC bf16; 4 elements/thread
template<int lgC, int lgHW, int lgW, int ST, bool PN>
__global__ __launch_bounds__(256) void bn_add_relu_nhwc(
    const unsigned short* __restrict__ x,
    const unsigned short* __restrict__ prev,
    unsigned short* __restrict__ outp,
    const float* __restrict__ stats, const float* __restrict__ pstats,
    int prevC, int padF, float invN, float pinvN, int n4)
{
    int i4 = blockIdx.x*256 + threadIdx.x;
    if (i4 >= n4) return;
    constexpr int C = 1<<lgC, HW = 1<<lgHW, W = 1<<lgW;
    const int i  = i4*4;
    const int c0 = i & (C-1);
    const int p  = (i >> lgC) & (HW-1);
    const int b  = i >> (lgC + lgHW);

    uint2 xv = ((const uint2*)x)[i4];
    float xf[4] = { bf2f(xv.x & 0xffffu), bf2f(xv.x >> 16),
                    bf2f(xv.y & 0xffffu), bf2f(xv.y >> 16) };
    float sc[4];
    if (ST == 1) {
        uint2 pv = ((const uint2*)prev)[i4];
        sc[0] = bf2f(pv.x & 0xffffu); sc[1] = bf2f(pv.x >> 16);
        sc[2] = bf2f(pv.y & 0xffffu); sc[3] = bf2f(pv.y >> 16);
        if (PN) {
            #pragma unroll
            for (int k = 0; k < 4; k++) {
                int c = c0 + k;
                float pm = pstats[c]*pinvN;
                float pvv = fmaxf(pstats[64+c]*pinvN - pm*pm, 0.f);
                sc[k] = fmaxf((sc[k] - pm)*rsqrtf(pvv + 1e-5f), 0.f);
            }
        }
    } else {
        int h = p >> lgW, wq = p & (W-1);
        int pp = (h << (lgW+2)) + 2*wq;
        #pragma unroll
        for (int k = 0; k < 4; k++) {
            int pc = c0 + k - padF;
            sc[k] = (pc >= 0 && pc < prevC)
                  ? bf2f((unsigned int)prev[((size_t)b*(HW*4) + pp)*prevC + pc]) : 0.f;
        }
    }
    float o[4];
    #pragma unroll
    for (int k = 0; k < 4; k++) {
        int c = c0 + k;
        float m = stats[c]*invN;
        float v = fmaxf(stats[64+c]*invN - m*m, 0.f);
        o[k] = fmaxf((xf[k]-m)*rsqrtf(v + 1e-5f) + sc[k], 0.f);
    }
    uint2 ov;
    ov.x = (unsigned)f2bf(o[0]) | ((unsigned)f2bf(o[1]) << 16);
    ov.y = (unsigned)f2bf(o[2]) | ((unsigned)f2bf(o[3]) << 16);
    ((uint2*)outp)[i4] = ov;
}

__device__ inline void stf(float* p, float v){ *p = v; }
__device__ inline void stf(__hip_bfloat16* p, float v){ *p = __float2bfloat16(v); }

// final bn_add fused into pool+fc: feat_c = mean_p relu(bn(x)+resid); out = feat@Wfc^T+bfc
template<typename T>
__global__ void poolfc_kernel(const unsigned short* __restrict__ x,
    const unsigned short* __restrict__ resid,
    const float* __restrict__ stats, float invN,
    const T* __restrict__ Wfc, const T* __restrict__ bfc,
    T* __restrict__ out, const int* flag, int want)
{
    if (flag_skip(flag, want)) return;
    int b = blockIdx.x;
    int c = threadIdx.x; // 64 threads
    float m = stats[c]*invN;
    float v = fmaxf(stats[64+c]*invN - m*m, 0.f);
    float rs = rsqrtf(v + 1e-5f);
    float s = 0.f;
    #pragma unroll
    for (int p = 0; p < 64; p++) {
        size_t idx = ((size_t)b*64 + p)*64 + c;
        float xv = bf2f((unsigned int)x[idx]);
        float rv = bf2f((unsigned int)resid[idx]);
        s += fmaxf((xv - m)*rs + rv, 0.f);
    }
    __shared__ float feat[64];
    feat[c] = s * (1.f/64.f);
    __syncthreads();
    if (c < 10) {
        float o = ldf(bfc + c);
        for (int k = 0; k < 64; k++)
            o += feat[k] * ldf(Wfc + c*64 + k);
        stf(out + b*10 + c, o);
    }
}

extern "C" void kernel_launch(void* const* d_in, const int* in_sizes, int n_in,
                              void* d_out, int out_size, void* d_ws, size_t ws_size,
                              hipStream_t stream)
{
    char* ws = (char*)d_ws;
    float* wflat = (float*)(ws);                            // DTOT fp32
    float* stats = (float*)(ws + 1114112);                  // 19 x 256 fp32
    int*   flag  = (int*)  (ws + 1146880);
    unsigned short* WT = (unsigned short*)(ws + 1179648);   // 269312 bf16
    unsigned short* curA = (unsigned short*)(ws + 1720320);               // 33.5MB
    unsigned short* curB = (unsigned short*)(ws + 1720320 + 33554432ULL); // 33.5MB (l0 raw)
    unsigned short* f1   = (unsigned short*)(ws + 1720320 + 67108864ULL);
    unsigned short* f2   = (unsigned short*)(ws + 1720320 + 100663296ULL);

    hipMemsetAsync(stats, 0, 32768, stream);
    detect_kernel<<<1, 256, 0, stream>>>((const unsigned short*)d_in[0], flag);

    wflat_kernel<__hip_bfloat16><<<(DTOT+255)/256, 256, 0, stream>>>(
        (const __hip_bfloat16*)d_in[1], (const __hip_bfloat16*)d_in[2],
        (const __hip_bfloat16*)d_in[3], wflat, DTOT, flag, 1);
    wflat_kernel<float><<<(DTOT+255)/256, 256, 0, stream>>>(
        (const float*)d_in[1], (const float*)d_in[2],
        (const float*)d_in[3], wflat, DTOT, flag, 0);

    {
        dim3 g(3, 64, 19);
        wprep_kernel<<<g, 192, 0, stream>>>(wflat, WT);
    }

    static const int WTOFF[NLAYER] = {0,0,2560,5120,7680,10240,12800,15360,20480,29696,
        38912,48128,57344,66560,84992,121856,158720,195584,232448};
    const float iN32 = 1.f/1048576.f;   // B*32*32
    const float iN16 = 1.f/262144.f;    // B*16*16
    const float iN8  = 1.f/65536.f;     // B*8*8

    // ---- layer 0 ----
    conv_l0<__hip_bfloat16><<<2*BATCH,512,0,stream>>>(
        (const __hip_bfloat16*)d_in[0], wflat, curB, flag, 1);
    conv_l0<float><<<2*BATCH,512,0,stream>>>(
        (const float*)d_in[0], wflat, curB, flag, 0);
    stats16_kernel<<<512,256,0,stream>>>(curB, stats, 4194304);

    // b0
    conv_mfma<16,16,32,32,1,false,false><<<BATCH,256,0,stream>>>(
        curB, nullptr, nullptr, WT + WTOFF[1], f1, stats + 1*256, stats, iN32, nullptr, 0.f);
    conv_mfma<16,16,32,32,1,false,false><<<BATCH,256,0,stream>>>(
        f1, nullptr, nullptr, WT + WTOFF[2], f2, stats + 2*256, stats + 1*256, iN32, nullptr, 0.f);
    // b1: fused bn_add(b0) [PN=l0 stats]; resid -> curA
    conv_mfma<16,16,32,32,1,true,true><<<BATCH,256,0,stream>>>(
        f2, curB, curA, WT + WTOFF[3], f1, stats + 3*256, stats + 2*256, iN32, stats, iN32);
    conv_mfma<16,16,32,32,1,false,false><<<BATCH,256,0,stream>>>(
        f1, nullptr, nullptr, WT + WTOFF[4], f2, stats + 4*256, stats + 3*256, iN32, nullptr, 0.f);
    // b2: fused bn_add(b1); resid -> curB
    conv_mfma<16,16,32,32,1,true,false><<<BATCH,256,0,stream>>>(
        f2, curA, curB, WT + WTOFF[5], f1, stats + 5*256, stats + 4*256, iN32, nullptr, 0.f);
    conv_mfma<16,16,32,32,1,false,false><<<BATCH,256,0,stream>>>(
        f1, nullptr, nullptr, WT + WTOFF[6], f2, stats + 6*256, stats + 5*256, iN32, nullptr, 0.f);
    // b3: fused bn_add(b2) into stride-2 conv-A(l7); resid -> curA
    conv_mfma<16,32,32,32,2,true,false><<<BATCH,256,0,stream>>>(
        f2, curB, curA, WT + WTOFF[7], f1, stats + 7*256, stats + 6*256, iN32, nullptr, 0.f);
    conv_mfma<32,32,16,16,1,false,false><<<BATCH,256,0,stream>>>(
        f1, nullptr, nullptr, WT + WTOFF[8], f2, stats + 8*256, stats + 7*256, iN16, nullptr, 0.f);
    bn_add_relu_nhwc<5,8,4,2,false><<<8192,256,0,stream>>>(
        f2, curA, curB, stats + 8*256, nullptr, 16, 8, iN16, 0.f, 2097152);
    // b4
    conv_mfma<32,32,16,16,1,false,false><<<BATCH,256,0,stream>>>(
        curB, nullptr, nullptr, WT + WTOFF[9], f1, stats + 9*256, nullptr, 0.f, nullptr, 0.f);
    conv_mfma<32,32,16,16,1,false,false><<<BATCH,256,0,stream>>>(
        f1, nullptr, nullptr, WT + WTOFF[10], f2, stats + 10*256, stats + 9*256, iN16, nullptr, 0.f);
    // b5: fused bn_add(b4); resid -> curA
    conv_mfma<32,32,16,16,1,true,false><<<BATCH,256,0,stream>>>(
        f2, curB, curA, WT + WTOFF[11], f1, stats + 11*256, stats + 10*256, iN16, nullptr, 0.f);
    conv_mfma<32,32,16,16,1,false,false><<<BATCH,256,0,stream>>>(
        f1, nullptr, nullptr, WT + WTOFF[12], f2, stats + 12*256, stats + 11*256, iN16, nullptr, 0.f);
    // b6: fused bn_add(b5) into stride-2 conv-A(l13); resid -> curB
    conv_mfma<32,64,16,16,2,true,false><<<BATCH,256,0,stream>>>(
        f2, curA, curB, WT + WTOFF[13], f1, stats + 13*256, stats + 12*256, iN16, nullptr, 0.f);
    conv_mfma<64,64,8,8,1,false,false><<<BATCH,256,0,stream>>>(
        f1, nullptr, nullptr, WT + WTOFF[14], f2, stats + 14*256, stats + 13*256, iN8, nullptr, 0.f);
    bn_add_relu_nhwc<6,6,3,2,false><<<4096,256,0,stream>>>(
        f2, curB, curA, stats + 14*256, nullptr, 32, 16, iN8, 0.f, 1048576);
    // b7
    conv_mfma<64,64,8,8,1,false,false><<<BATCH,256,0,stream>>>(
        curA, nullptr, nullptr, WT + WTOFF[15], f1, stats + 15*256, nullptr, 0.f, nullptr, 0.f);
    conv_mfma<64,64,8,8,1,false,false><<<BATCH,256,0,stream>>>(
        f1, nullptr, nullptr, WT + WTOFF[16], f2, stats + 16*256, stats + 15*256, iN8, nullptr, 0.f);
    // b8: fused bn_add(b7); resid -> curB
    conv_mfma<64,64,8,8,1,true,false><<<BATCH,256,0,stream>>>(
        f2, curA, curB, WT + WTOFF[17], f1, stats + 17*256, stats + 16*256, iN8, nullptr, 0.f);
    conv_mfma<64,64,8,8,1,false,false><<<BATCH,256,0,stream>>>(
        f1, nullptr, nullptr, WT + WTOFF[18], f2, stats + 18*256, stats + 17*256, iN8, nullptr, 0.f);

    // final bn_add(l18)+resid(curB) fused into pool+fc
    poolfc_kernel<__hip_bfloat16><<<BATCH, 64, 0, stream>>>(
        f2, curB, stats + 18*256, iN8,
        (const __hip_bfloat16*)d_in[4], (const __hip_bfloat16*)d_in[5],
        (__hip_bfloat16*)d_out, flag, 1);
    poolfc_kernel<float><<<BATCH, 64, 0, stream>>>(
        f2, curB, stats + 18*256, iN8,
        (const float*)d_in[4], (const float*)d_in[5],
        (float*)d_out, flag, 0);
}

// Round 18
// 707.356 us; speedup vs baseline: 1.1013x; 1.0248x over previous
//
#include <hip/hip_runtime.h>
#include <hip/hip_bf16.h>

#define BATCH 1024
#define NLAYER 19
#define DTOT 267696

typedef __attribute__((ext_vector_type(8))) short v8s;
typedef __attribute__((ext_vector_type(4))) float v4f;

__device__ inline float ldf(const float* p){ return *p; }
__device__ inline float ldf(const __hip_bfloat16* p){ return __bfloat162float(*p); }

__device__ inline unsigned short f2bf(float x){
    __hip_bfloat16 h = __float2bfloat16(x);
    return *reinterpret_cast<unsigned short*>(&h);
}
__device__ inline float bf2f(unsigned int u){
    return __uint_as_float(u << 16);
}

// ---- dtype detector: flag=1 if inputs bf16, 0 if f32 ----
__global__ void detect_kernel(const unsigned short* __restrict__ xraw, int* __restrict__ flag)
{
    __shared__ int bad;
    if (threadIdx.x == 0) bad = 0;
    __syncthreads();
    int lbad = 0;
    for (int i = threadIdx.x; i < 4096; i += 256) {
        unsigned e = (xraw[i] >> 7) & 0xFF;
        if (e >= 147) lbad++;
    }
    if (lbad) atomicAdd(&bad, lbad);
    __syncthreads();
    if (threadIdx.x == 0) *flag = (bad == 0) ? 1 : 0;
}

__device__ inline bool flag_skip(const int* flag, int want)
{
    if (flag == nullptr) return false;
    return (*(volatile const int*)flag) != want;
}

// w_flat = origin + new_param @ P
template<typename T>
__global__ void wflat_kernel(const T* __restrict__ origin,
                             const T* __restrict__ P,
                             const T* __restrict__ npar,
                             float* __restrict__ wout, int D,
                             const int* flag, int want)
{
    if (flag_skip(flag, want)) return;
    int d = blockIdx.x*256 + threadIdx.x;
    if (d >= D) return;
    float acc = ldf(origin + d);
    #pragma unroll 8
    for (int k = 0; k < 40; k++)
        acc += ldf(npar + k) * ldf(P + (long long)k*D + d);
    wout[d] = acc;
}

// ---- weight transform: wflat (OIHW fp32) -> W_T[l][cout][kpad] bf16, k = tap*Cin+ci
__global__ void wprep_kernel(const float* __restrict__ wflat, unsigned short* __restrict__ WT)
{
    static const int CINA[19]  = {3,16,16,16,16,16,16,16,32,32,32,32,32,32,64,64,64,64,64};
    static const int COUTA[19] = {16,16,16,16,16,16,16,32,32,32,32,32,32,64,64,64,64,64,64};
    static const int LGCA[19]  = {0,4,4,4,4,4,4,4,5,5,5,5,5,5,6,6,6,6,6};
    static const int KPADA[19] = {0,160,160,160,160,160,160,160,288,288,288,288,288,288,576,576,576,576,576};
    static const int WOFFA[19] = {0,432,2736,5040,7344,9648,11952,14256,18864,
        28080,37296,46512,55728,64944,83376,120240,157104,193968,230832};
    static const int WTOFFA[19]= {0,0,2560,5120,7680,10240,12800,15360,20480,29696,
        38912,48128,57344,66560,84992,121856,158720,195584,232448};
    int l = blockIdx.z;
    if (l == 0) return;
    int co = blockIdx.y;
    if (co >= COUTA[l]) return;
    int kp = blockIdx.x*192 + threadIdx.x;
    if (kp >= KPADA[l]) return;
    int cin = CINA[l];
    float v = 0.f;
    if (kp < 9*cin) {
        int tap = kp >> LGCA[l];
        int ci  = kp & (cin - 1);
        v = wflat[WOFFA[l] + (co*cin + ci)*9 + tap];
    }
    WT[WTOFFA[l] + co*KPADA[l] + kp] = f2bf(v);
}

__device__ inline void ldpair(const float* base, int p, float& x0, float& x1){
    const float2 v = ((const float2*)base)[p];
    x0 = v.x; x1 = v.y;
}
__device__ inline void ldpair(const __hip_bfloat16* base, int p, float& x0, float& x1){
    unsigned u = ((const unsigned int*)base)[p];
    x0 = __uint_as_float(u << 16);
    x1 = __uint_as_float(u & 0xffff0000u);
}

// ---- layer 0: direct conv (Cin=3), NCHW input -> NHWC bf16 raw ----
template<typename T>
__global__ __launch_bounds__(512) void conv_l0(
    const T* __restrict__ in, const float* __restrict__ wt,
    unsigned short* __restrict__ out,
    const int* flag, int want)
{
    if (flag_skip(flag, want)) return;
    constexpr int WP = 38, W2 = 19;
    __shared__ uint2 smem2[2048];
    __shared__ unsigned int in_su[3*18*W2];
    __shared__ float w_s[432];

    const int tid  = threadIdx.x;
    const int b    = blockIdx.x >> 1;
    const int half = blockIdx.x & 1;
    const int row0 = half*16 - 1;

    {
        const T* inb = in + (size_t)b*3072;
        for (int i = tid; i < 864; i += 512) {
            int w2 = i & 15, lr = (i >> 4) % 18, c = i / 288;
            int ih = row0 + lr;
            unsigned int pk = 0u;
            if ((unsigned)ih < 32u) {
                float x0, x1;
                ldpair(inb, (c*32 + ih)*16 + w2, x0, x1);
                pk = (unsigned int)f2bf(x0) | ((unsigned int)f2bf(x1) << 16);
            }
            in_su[(c*18 + lr)*W2 + 1 + w2] = pk;
        }
        unsigned short* in_ss = (unsigned short*)in_su;
        for (int i = tid; i < 54; i += 512) {
            in_ss[i*WP + 1]  = 0;
            in_ss[i*WP + 34] = 0;
        }
        for (int i = tid; i < 432; i += 512) w_s[i] = wt[i];
    }
    __syncthreads();

    const int r   = tid >> 5;
    const int col = tid & 31;

    float acc[16];
    #pragma unroll
    for (int c = 0; c < 16; c++) acc[c] = 0.f;

    #pragma unroll
    for (int ci = 0; ci < 3; ci++) {
        #pragma unroll
        for (int kh = 0; kh < 3; kh++) {
            const unsigned int* up = in_su + (ci*18 + r + kh)*W2 + ((col+1) >> 1);
            unsigned int u0 = up[0], u1 = up[1];
            bool odd = (col & 1);
            float s1 = odd ? bf2f(u0 & 0xffffu) : bf2f(u0 >> 16);
            float s2 = odd ? bf2f(u0 >> 16)     : bf2f(u1 & 0xffffu);
            float s3 = odd ? bf2f(u1 & 0xffffu) : bf2f(u1 >> 16);
            const float* wp = w_s + ci*9 + kh*3;
            #pragma unroll
            for (int co = 0; co < 16; co++) {
                acc[co] += s1*wp[co*27+0] + s2*wp[co*27+1] + s3*wp[co*27+2];
            }
        }
    }

    #pragma unroll
    for (int j = 0; j < 4; j++) {
        uint2 v;
        v.x = (unsigned)f2bf(acc[4*j+0]) | ((unsigned)f2bf(acc[4*j+1]) << 16);
        v.y = (unsigned)f2bf(acc[4*j+2]) | ((unsigned)f2bf(acc[4*j+3]) << 16);
        smem2[tid*4 + (j ^ (tid & 3))] = v;
    }
    __syncthreads();
    {
        uint2* ob = (uint2*)(out + (size_t)b*16384 + half*8192);
        #pragma unroll
        for (int it = 0; it < 4; it++) {
            int s = it*512 + tid;
            int phys = (s & ~3) | ((s & 3) ^ ((s >> 2) & 3));
            ob[s] = smem2[phys];
        }
    }
}

// ---- per-channel sum/sumsq over NHWC bf16, C=16; 32 atomics/block ----
__global__ __launch_bounds__(256) void stats16_kernel(
    const unsigned short* __restrict__ x, float* __restrict__ stats, int n4)
{
    __shared__ float red[4][32];
    int t = blockIdx.x*256 + threadIdx.x;
    const int stride = gridDim.x*256;
    float s[4] = {0,0,0,0}, q[4] = {0,0,0,0};
    for (int i = t; i < n4; i += stride) {
        uint2 v = ((const uint2*)x)[i];
        float f0 = bf2f(v.x & 0xffffu), f1 = bf2f(v.x >> 16);
        float f2_ = bf2f(v.y & 0xffffu), f3 = bf2f(v.y >> 16);
        s[0] += f0; q[0] += f0*f0;
        s[1] += f1; q[1] += f1*f1;
        s[2] += f2_; q[2] += f2_*f2_;
        s[3] += f3; q[3] += f3*f3;
    }
    #pragma unroll
    for (int off = 4; off < 64; off <<= 1) {
        #pragma unroll
        for (int k = 0; k < 4; k++) {
            s[k] += __shfl_xor(s[k], off);
            q[k] += __shfl_xor(q[k], off);
        }
    }
    const int lane = threadIdx.x & 63, w = threadIdx.x >> 6;
    if (lane < 4) {
        #pragma unroll
        for (int k = 0; k < 4; k++) {
            red[w][lane*4 + k]      = s[k];
            red[w][16 + lane*4 + k] = q[k];
        }
    }
    __syncthreads();
    if (threadIdx.x < 32) {
        float v = red[0][threadIdx.x] + red[1][threadIdx.x]
                + red[2][threadIdx.x] + red[3][threadIdx.x];
        atomicAdd(&stats[(threadIdx.x < 16) ? threadIdx.x : (48 + threadIdx.x)], v);
    }
}

// ---- MFMA implicit-GEMM 3x3 conv, one block (4 waves) per image ----
// FUSE : staging performs preceding stride-1 bn_add (elementwise residual).
// FUSE2: staging performs preceding stride-2 bn_add (residual = 2x-res gather,
//        channel pad 8-aligned -> whole uint4 group valid or zero).
template<int CIN, int COUT, int HIN, int WIN, int ST, bool FUSE, bool PN,
         bool FUSE2, int PREVC, int PADF>
__global__ __launch_bounds__(256, 4) void conv_mfma(
    const unsigned short* __restrict__ src, const unsigned short* __restrict__ prev,
    unsigned short* __restrict__ resid,
    const unsigned short* __restrict__ wt,
    unsigned short* __restrict__ out, float* __restrict__ stats,
    const float* __restrict__ nstats, float ninvN,
    const float* __restrict__ pstats, float pinvN)
{
    constexpr int HO = HIN/ST, WO = WIN/ST, M = HO*WO, MT = M/16;
    constexpr int NT = COUT/16;
    constexpr int K  = 9*CIN;
    constexpr int S  = (K + 31)/32;
    constexpr int KPAD = S*32;
    constexpr int lgC  = (CIN==16)?4:(CIN==32)?5:6;
    constexpr int lgWI = (WIN==32)?5:(WIN==16)?4:3;
    constexpr int lgWO = (WO==32)?5:(WO==16)?4:3;
    constexpr int CMASK = CIN/8 - 1;
    constexpr int JITER = (NT==1)? MT/4 : (NT==2)? MT/2 : MT;
    static_assert(M*COUT <= CIN*HIN*WIN, "out_s fits in in_s");

    __shared__ unsigned short in_s[CIN*HIN*WIN];   // input, then output bounce
    __shared__ float red[128];
    __shared__ float nm[64], nv[64];
    __shared__ float pm_s[64], pv_s[64];
    __shared__ uint4 zq;

    const int tid = threadIdx.x;
    const int b   = blockIdx.x;

    if (tid == 0) { zq.x = 0; zq.y = 0; zq.z = 0; zq.w = 0; }
    if (nstats != nullptr && tid < CIN) {
        float m = nstats[tid]*ninvN;
        float v = fmaxf(nstats[64+tid]*ninvN - m*m, 0.f);
        nm[tid] = m; nv[tid] = rsqrtf(v + 1e-5f);
    }
    if (PN && tid < CIN) {
        float m = pstats[tid]*pinvN;
        float v = fmaxf(pstats[64+tid]*pinvN - m*m, 0.f);
        pm_s[tid] = m; pv_s[tid] = rsqrtf(v + 1e-5f);
    }
    __syncthreads();

    // ---- staging ----
    {
        const uint4* sb4 = (const uint4*)(src + (size_t)b*(HIN*WIN)*CIN);
        constexpr int NP4 = CIN*HIN*WIN/8;
        if (FUSE) {
            const uint4* pb4 = (const uint4*)(prev + (size_t)b*(HIN*WIN)*CIN);
            uint4* rb4 = (uint4*)(resid + (size_t)b*(HIN*WIN)*CIN);
            for (int i = tid; i < NP4; i += 256) {
                uint4 v = sb4[i];
                uint4 pw = pb4[i];
                int e0 = i << 3;
                int c0 = e0 & (CIN-1);
                int p  = e0 >> lgC;
                float f[8] = { bf2f(v.x & 0xffffu), bf2f(v.x >> 16),
                               bf2f(v.y & 0xffffu), bf2f(v.y >> 16),
                               bf2f(v.z & 0xffffu), bf2f(v.z >> 16),
                               bf2f(v.w & 0xffffu), bf2f(v.w >> 16) };
                float g[8] = { bf2f(pw.x & 0xffffu), bf2f(pw.x >> 16),
                               bf2f(pw.y & 0xffffu), bf2f(pw.y >> 16),
                               bf2f(pw.z & 0xffffu), bf2f(pw.z >> 16),
                               bf2f(pw.w & 0xffffu), bf2f(pw.w >> 16) };
                #pragma unroll
                for (int k = 0; k < 8; k++) {
                    int c = c0 + k;
                    float fx = (f[k] - nm[c])*nv[c];
                    float gv = g[k];
                    if (PN) gv = fmaxf((gv - pm_s[c])*pv_s[c], 0.f);
                    f[k] = fmaxf(fx + gv, 0.f);
                }
                uint4 o;
                o.x = (unsigned)f2bf(f[0]) | ((unsigned)f2bf(f[1]) << 16);
                o.y = (unsigned)f2bf(f[2]) | ((unsigned)f2bf(f[3]) << 16);
                o.z = (unsigned)f2bf(f[4]) | ((unsigned)f2bf(f[5]) << 16);
                o.w = (unsigned)f2bf(f[6]) | ((unsigned)f2bf(f[7]) << 16);
                rb4[i] = o;
                int csw = c0 ^ ((p & CMASK) << 3);
                *(uint4*)(in_s + (p << lgC) + csw) = o;
            }
        } else if (FUSE2) {
            // prev dims: (2*HIN)x(2*WIN)xPREVC; group valid iff pc0 in [0,PREVC-8]
            uint4* rb4 = (uint4*)(resid + (size_t)b*(HIN*WIN)*CIN);
            for (int i = tid; i < NP4; i += 256) {
                uint4 v = sb4[i];
                int e0 = i << 3;
                int c0 = e0 & (CIN-1);
                int p  = e0 >> lgC;
                int h  = p >> lgWI, wq = p & (WIN-1);
                int pp = (h << (lgWI+2)) + 2*wq;
                int pc0 = c0 - PADF;
                bool pv = (pc0 >= 0) && (pc0 <= PREVC - 8);
                uint4 pw;
                pw.x = 0; pw.y = 0; pw.z = 0; pw.w = 0;
                if (pv) pw = *(const uint4*)(prev + ((size_t)b*(HIN*WIN*4) + pp)*PREVC + pc0);
                float f[8] = { bf2f(v.x & 0xffffu), bf2f(v.x >> 16),
                               bf2f(v.y & 0xffffu), bf2f(v.y >> 16),
                               bf2f(v.z & 0xffffu), bf2f(v.z >> 16),
                               bf2f(v.w & 0xffffu), bf2f(v.w >> 16) };
                float g[8] = { bf2f(pw.x & 0xffffu), bf2f(pw.x >> 16),
                               bf2f(pw.y & 0xffffu), bf2f(pw.y >> 16),
                               bf2f(pw.z & 0xffffu), bf2f(pw.z >> 16),
                               bf2f(pw.w & 0xffffu), bf2f(pw.w >> 16) };
                #pragma unroll
                for (int k = 0; k < 8; k++) {
                    int c = c0 + k;
                    f[k] = fmaxf((f[k] - nm[c])*nv[c] + g[k], 0.f);
                }
                uint4 o;
                o.x = (unsigned)f2bf(f[0]) | ((unsigned)f2bf(f[1]) << 16);
                o.y = (unsigned)f2bf(f[2]) | ((unsigned)f2bf(f[3]) << 16);
                o.z = (unsigned)f2bf(f[4]) | ((unsigned)f2bf(f[5]) << 16);
                o.w = (unsigned)f2bf(f[6]) | ((unsigned)f2bf(f[7]) << 16);
                rb4[i] = o;
                int csw = c0 ^ ((p & CMASK) << 3);
                *(uint4*)(in_s + (p << lgC) + csw) = o;
            }
        } else if (nstats == nullptr) {
            for (int i = tid; i < NP4; i += 256) {
                uint4 v = sb4[i];
                int e0 = i << 3;
                int c0 = e0 & (CIN-1);
                int p  = e0 >> lgC;
                int csw = c0 ^ ((p & CMASK) << 3);
                *(uint4*)(in_s + (p << lgC) + csw) = v;
            }
        } else {
            for (int i = tid; i < NP4; i += 256) {
                uint4 v = sb4[i];
                int e0 = i << 3;
                int c0 = e0 & (CIN-1);
                int p  = e0 >> lgC;
                float f[8] = { bf2f(v.x & 0xffffu), bf2f(v.x >> 16),
                               bf2f(v.y & 0xffffu), bf2f(v.y >> 16),
                               bf2f(v.z & 0xffffu), bf2f(v.z >> 16),
                               bf2f(v.w & 0xffffu), bf2f(v.w >> 16) };
                #pragma unroll
                for (int k = 0; k < 8; k++) {
                    int c = c0 + k;
                    f[k] = fmaxf((f[k] - nm[c])*nv[c], 0.f);
                }
                uint4 o;
                o.x = (unsigned)f2bf(f[0]) | ((unsigned)f2bf(f[1]) << 16);
                o.y = (unsigned)f2bf(f[2]) | ((unsigned)f2bf(f[3]) << 16);
                o.z = (unsigned)f2bf(f[4]) | ((unsigned)f2bf(f[5]) << 16);
                o.w = (unsigned)f2bf(f[6]) | ((unsigned)f2bf(f[7]) << 16);
                int csw = c0 ^ ((p & CMASK) << 3);
                *(uint4*)(in_s + (p << lgC) + csw) = o;
            }
        }
    }
    __syncthreads();

    const int w   = tid >> 6;
    const int ln  = tid & 63;
    const int l15 = ln & 15;
    const int q   = ln >> 4;

    int n0, mt0, step;
    if (NT == 1)      { n0 = 0;         mt0 = w;      step = 4; }
    else if (NT == 2) { n0 = (w&1)*16;  mt0 = w>>1;   step = 2; }
    else              { n0 = w*16;      mt0 = 0;      step = 1; }

    v8s Bf[S];
    {
        const unsigned short* wb = wt + (size_t)(n0 + l15)*KPAD + q*8;
        #pragma unroll
        for (int s = 0; s < S; s++)
            Bf[s] = *(const v8s*)(wb + 32*s);
    }

    int dh1s[S], dw1s[S];
    int c0q = (CIN==16) ? ((q & 1) << 3) : (q << 3);
    if (CIN == 16) {
        int tq = q >> 1;
        #pragma unroll
        for (int s = 0; s < S; s++) {
            int tap = 2*s + tq;
            int dh = (tap*11) >> 5;
            int dw = tap - 3*dh;
            dh1s[s] = (tap >= 9) ? -1000 : (dh - 1);
            dw1s[s] = dw - 1;
        }
    }

    v4f acc[JITER];
    #pragma unroll
    for (int j = 0; j < JITER; j++) acc[j] = v4f{0.f,0.f,0.f,0.f};

    #pragma unroll
    for (int j = 0; j < JITER; j++) {
        const int mt  = mt0 + j*step;
        const int p   = mt*16 + l15;
        const int ihb = (p >> lgWO) * ST;
        const int iwb = (p & (WO-1)) * ST;
        #pragma unroll
        for (int s = 0; s < S; s++) {
            int dh1, dw1, c0s;
            if (CIN == 16) { dh1 = dh1s[s]; dw1 = dw1s[s]; c0s = c0q; }
            else {
                const int tap = (CIN == 32) ? s : (s >> 1);
                dh1 = tap/3 - 1; dw1 = tap%3 - 1;
                c0s = c0q + ((CIN == 64) ? ((s & 1) << 5) : 0);
            }
            int ih = ihb + dh1, iw = iwb + dw1;
            bool valid = ((unsigned)ih < (unsigned)HIN) && ((unsigned)iw < (unsigned)WIN);
            int pp  = (ih << lgWI) + iw;
            int csw = c0s ^ ((pp & CMASK) << 3);
            int eoff = (pp << lgC) + csw;
            const v8s* ap = valid ? (const v8s*)(in_s + eoff) : (const v8s*)&zq;
            v8s Af = *ap;
            acc[j] = __builtin_amdgcn_mfma_f32_16x16x32_bf16(Af, Bf[s], acc[j], 0, 0, 0);
        }
    }
    __syncthreads();   // all in_s reads complete -> reuse as output bounce

    unsigned short* out_s = in_s;
    float sa = 0.f, qa = 0.f;
    #pragma unroll
    for (int j = 0; j < JITER; j++) {
        const int mt = mt0 + j*step;
        #pragma unroll
        for (int r2 = 0; r2 < 4; r2++) {
            float v = acc[j][r2];
            out_s[(mt*16 + q*4 + r2)*COUT + n0 + l15] = f2bf(v);
            sa += v; qa += v*v;
        }
    }
    __syncthreads();

    {
        constexpr int NIT = (M*COUT/8)/256;
        uint4* ob4 = (uint4*)(out + (size_t)b*M*COUT);
        const uint4* os4 = (const uint4*)in_s;
        #pragma unroll
        for (int it = 0; it < NIT; it++)
            ob4[it*256 + tid] = os4[it*256 + tid];
    }

    sa += __shfl_xor(sa, 16); sa += __shfl_xor(sa, 32);
    qa += __shfl_xor(qa, 16); qa += __shfl_xor(qa, 32);
    if (q == 0) {
        red[(w*16 + l15)*2]     = sa;
        red[(w*16 + l15)*2 + 1] = qa;
    }
    __syncthreads();
    if (tid < COUT) {
        float S2, Q2;
        if (NT == 1) {
            S2 = red[tid*2] + red[(16+tid)*2] + red[(32+tid)*2] + red[(48+tid)*2];
            Q2 = red[tid*2+1] + red[(16+tid)*2+1] + red[(32+tid)*2+1] + red[(48+tid)*2+1];
        } else if (NT == 2) {
            int w0 = tid >> 4, cl = tid & 15;
            S2 = red[((w0*16)+cl)*2]     + red[(((w0+2)*16)+cl)*2];
            Q2 = red[((w0*16)+cl)*2 + 1] + red[(((w0+2)*16)+cl)*2 + 1];
        } else {
            int w0 = tid >> 4, cl = tid & 15;
            S2 = red[((w0*16)+cl)*2];
            Q2 = red[((w0*16)+cl)*2 + 1];
        }
        atomicAdd(&stats[tid],      S2);
        atomicAdd(&stats[64 + tid], Q2);
    }
}

__device__ inline void stf(float* p, float v){ *p = v; }
__device__ inline void stf(__hip_bfloat16* p, float v){ *p = __float2bfloat16(v); }

// final bn_add fused into pool+fc
template<typename T>
__global__ void poolfc_kernel(const unsigned short* __restrict__ x,
    const unsigned short* __restrict__ resid,
    const float* __restrict__ stats, float invN,
    const T* __restrict__ Wfc, const T* __restrict__ bfc,
    T* __restrict__ out, const int* flag, int want)
{
    if (flag_skip(flag, want)) return;
    int b = blockIdx.x;
    int c = threadIdx.x; // 64 threads
    float m = stats[c]*invN;
    float v = fmaxf(stats[64+c]*invN - m*m, 0.f);
    float rs = rsqrtf(v + 1e-5f);
    float s = 0.f;
    #pragma unroll
    for (int p = 0; p < 64; p++) {
        size_t idx = ((size_t)b*64 + p)*64 + c;
        float xv = bf2f((unsigned int)x[idx]);
        float rv = bf2f((unsigned int)resid[idx]);
        s += fmaxf((xv - m)*rs + rv, 0.f);
    }
    __shared__ float feat[64];
    feat[c] = s * (1.f/64.f);
    __syncthreads();
    if (c < 10) {
        float o = ldf(bfc + c);
        for (int k = 0; k < 64; k++)
            o += feat[k] * ldf(Wfc + c*64 + k);
        stf(out + b*10 + c, o);
    }
}

extern "C" void kernel_launch(void* const* d_in, const int* in_sizes, int n_in,
                              void* d_out, int out_size, void* d_ws, size_t ws_size,
                              hipStream_t stream)
{
    char* ws = (char*)d_ws;
    float* wflat = (float*)(ws);                            // DTOT fp32
    float* stats = (float*)(ws + 1114112);                  // 19 x 256 fp32
    int*   flag  = (int*)  (ws + 1146880);
    unsigned short* WT = (unsigned short*)(ws + 1179648);   // 269312 bf16
    unsigned short* curA = (unsigned short*)(ws + 1720320);               // 33.5MB
    unsigned short* curB = (unsigned short*)(ws + 1720320 + 33554432ULL); // 33.5MB (l0 raw)
    unsigned short* f1   = (unsigned short*)(ws + 1720320 + 67108864ULL);
    unsigned short* f2   = (unsigned short*)(ws + 1720320 + 100663296ULL);

    hipMemsetAsync(stats, 0, 32768, stream);
    detect_kernel<<<1, 256, 0, stream>>>((const unsigned short*)d_in[0], flag);

    wflat_kernel<__hip_bfloat16><<<(DTOT+255)/256, 256, 0, stream>>>(
        (const __hip_bfloat16*)d_in[1], (const __hip_bfloat16*)d_in[2],
        (const __hip_bfloat16*)d_in[3], wflat, DTOT, flag, 1);
    wflat_kernel<float><<<(DTOT+255)/256, 256, 0, stream>>>(
        (const float*)d_in[1], (const float*)d_in[2],
        (const float*)d_in[3], wflat, DTOT, flag, 0);

    {
        dim3 g(3, 64, 19);
        wprep_kernel<<<g, 192, 0, stream>>>(wflat, WT);
    }

    static const int WTOFF[NLAYER] = {0,0,2560,5120,7680,10240,12800,15360,20480,29696,
        38912,48128,57344,66560,84992,121856,158720,195584,232448};
    const float iN32 = 1.f/1048576.f;   // B*32*32
    const float iN16 = 1.f/262144.f;    // B*16*16
    const float iN8  = 1.f/65536.f;     // B*8*8

    // ---- layer 0 ----
    conv_l0<__hip_bfloat16><<<2*BATCH,512,0,stream>>>(
        (const __hip_bfloat16*)d_in[0], wflat, curB, flag, 1);
    conv_l0<float><<<2*BATCH,512,0,stream>>>(
        (const float*)d_in[0], wflat, curB, flag, 0);
    stats16_kernel<<<512,256,0,stream>>>(curB, stats, 4194304);

    // b0
    conv_mfma<16,16,32,32,1,false,false,false,0,0><<<BATCH,256,0,stream>>>(
        curB, nullptr, nullptr, WT + WTOFF[1], f1, stats + 1*256, stats, iN32, nullptr, 0.f);
    conv_mfma<16,16,32,32,1,false,false,false,0,0><<<BATCH,256,0,stream>>>(
        f1, nullptr, nullptr, WT + WTOFF[2], f2, stats + 2*256, stats + 1*256, iN32, nullptr, 0.f);
    // b1: fused bn_add(b0) [PN=l0 stats]; resid -> curA
    conv_mfma<16,16,32,32,1,true,true,false,0,0><<<BATCH,256,0,stream>>>(
        f2, curB, curA, WT + WTOFF[3], f1, stats + 3*256, stats + 2*256, iN32, stats, iN32);
    conv_mfma<16,16,32,32,1,false,false,false,0,0><<<BATCH,256,0,stream>>>(
        f1, nullptr, nullptr, WT + WTOFF[4], f2, stats + 4*256, stats + 3*256, iN32, nullptr, 0.f);
    // b2: fused bn_add(b1); resid -> curB
    conv_mfma<16,16,32,32,1,true,false,false,0,0><<<BATCH,256,0,stream>>>(
        f2, curA, curB, WT + WTOFF[5], f1, stats + 5*256, stats + 4*256, iN32, nullptr, 0.f);
    conv_mfma<16,16,32,32,1,false,false,false,0,0><<<BATCH,256,0,stream>>>(
        f1, nullptr, nullptr, WT + WTOFF[6], f2, stats + 6*256, stats + 5*256, iN32, nullptr, 0.f);
    // b3: fused bn_add(b2) into stride-2 conv-A(l7); resid -> curA (32²,16ch)
    conv_mfma<16,32,32,32,2,true,false,false,0,0><<<BATCH,256,0,stream>>>(
        f2, curB, curA, WT + WTOFF[7], f1, stats + 7*256, stats + 6*256, iN32, nullptr, 0.f);
    conv_mfma<32,32,16,16,1,false,false,false,0,0><<<BATCH,256,0,stream>>>(
        f1, nullptr, nullptr, WT + WTOFF[8], f2, stats + 8*256, stats + 7*256, iN16, nullptr, 0.f);
    // b4: FUSE2 bn_add(b3, stride2 shortcut from curA) into conv-A(l9); resid -> curB
    conv_mfma<32,32,16,16,1,false,false,true,16,8><<<BATCH,256,0,stream>>>(
        f2, curA, curB, WT + WTOFF[9], f1, stats + 9*256, stats + 8*256, iN16, nullptr, 0.f);
    conv_mfma<32,32,16,16,1,false,false,false,0,0><<<BATCH,256,0,stream>>>(
        f1, nullptr, nullptr, WT + WTOFF[10], f2, stats + 10*256, stats + 9*256, iN16, nullptr, 0.f);
    // b5: fused bn_add(b4); resid -> curA
    conv_mfma<32,32,16,16,1,true,false,false,0,0><<<BATCH,256,0,stream>>>(
        f2, curB, curA, WT + WTOFF[11], f1, stats + 11*256, stats + 10*256, iN16, nullptr, 0.f);
    conv_mfma<32,32,16,16,1,false,false,false,0,0><<<BATCH,256,0,stream>>>(
        f1, nullptr, nullptr, WT + WTOFF[12], f2, stats + 12*256, stats + 11*256, iN16, nullptr, 0.f);
    // b6: fused bn_add(b5) into stride-2 conv-A(l13); resid -> curB (16²,32ch)
    conv_mfma<32,64,16,16,2,true,false,false,0,0><<<BATCH,256,0,stream>>>(
        f2, curA, curB, WT + WTOFF[13], f1, stats + 13*256, stats + 12*256, iN16, nullptr, 0.f);
    conv_mfma<64,64,8,8,1,false,false,false,0,0><<<BATCH,256,0,stream>>>(
        f1, nullptr, nullptr, WT + WTOFF[14], f2, stats + 14*256, stats + 13*256, iN8, nullptr, 0.f);
    // b7: FUSE2 bn_add(b6, stride2 shortcut from curB) into conv-A(l15); resid -> curA
    conv_mfma<64,64,8,8,1,false,false,true,32,16><<<BATCH,256,0,stream>>>(
        f2, curB, curA, WT + WTOFF[15], f1, stats + 15*256, stats + 14*256, iN8, nullptr, 0.f);
    conv_mfma<64,64,8,8,1,false,false,false,0,0><<<BATCH,256,0,stream>>>(
        f1, nullptr, nullptr, WT + WTOFF[16], f2, stats + 16*256, stats + 15*256, iN8, nullptr, 0.f);
    // b8: fused bn_add(b7); resid -> curB
    conv_mfma<64,64,8,8,1,true,false,false,0,0><<<BATCH,256,0,stream>>>(
        f2, curA, curB, WT + WTOFF[17], f1, stats + 17*256, stats + 16*256, iN8, nullptr, 0.f);
    conv_mfma<64,64,8,8,1,false,false,false,0,0><<<BATCH,256,0,stream>>>(
        f1, nullptr, nullptr, WT + WTOFF[18], f2, stats + 18*256, stats + 17*256, iN8, nullptr, 0.f);

    // final bn_add(l18)+resid(curB) fused into pool+fc
    poolfc_kernel<__hip_bfloat16><<<BATCH, 64, 0, stream>>>(
        f2, curB, stats + 18*256, iN8,
        (const __hip_bfloat16*)d_in[4], (const __hip_bfloat16*)d_in[5],
        (__hip_bfloat16*)d_out, flag, 1);
    poolfc_kernel<float><<<BATCH, 64, 0, stream>>>(
        f2, curB, stats + 18*256, iN8,
        (const float*)d_in[4], (const float*)d_in[5],
        (float*)d_out, flag, 0);
}